// Round 1
// baseline (2109.575 us; speedup 1.0000x reference)
//
#include <hip/hip_runtime.h>
#include <hip/hip_bf16.h>
#include <math.h>

// Binarized ConvNet, exact-sign implementation.
// Pipeline:
//  k1: conv1 (f64) -> t1 bits -> pooled s1 bits (packed u16 rows) + cnt1 popcount
//  k2: bn1 constants (f64), W2 sign bits, C2 offsets
//  k3: conv2 via XOR-popcount (exact integer q_c) + f64 combine -> t2 -> pooled s2 (+cnt2)
//  k4a/k4b: bn2 constants, bn3 per-feature constants (A3,B3) from s2 column sums
//  k5: fc1 per-output offsets c1j
//  k6: fc1 (f64 +-B3 accumulation) -> t4 bytes
//  k7: bn4 constants (A4,B4) from t4 column sums + fc2 offsets C3
//  k8: fc2 (f64) -> out f32

#define NBATCH 4096
static const double EPSD = 1e-5;

// ---------------- ws layout (bytes) ----------------
#define O_CNT1   0         // 64 u32
#define O_CNT2   256       // 96 u32
#define O_ALPHA1 1024      // 64 f64
#define O_BETA1  1536      // 64 f64
#define O_C2     2048      // 96 f64
#define O_ALPHA2 3072      // 96 f64
#define O_BETA2  3840      // 96 f64
#define O_A3     4608      // 1536 f64
#define O_B3     16896     // 1536 f64
#define O_C1J    29184     // 1024 f64
#define O_A4     37376     // 1024 f64
#define O_B4     45568     // 1024 f64
#define O_C3     53760     // 10 f64
#define O_W2BITS 65536     // 96*64 u32 = 24576
#define O_S1P    131072    // 4096*64*12 u16 = 6291456
#define O_S2     6422528   // 4096*1536 i8 = 6291456
#define O_T4     12713984  // 4096*1024 i8 = 4194304
// total ~16.9 MB

// ---------------------------------------------------------------- k1: conv1
__global__ __launch_bounds__(256) void k1_conv1(
    const float* __restrict__ x, const float* __restrict__ w1,
    const float* __restrict__ b1c, const float* __restrict__ g1,
    unsigned short* __restrict__ s1p, unsigned int* __restrict__ cnt1)
{
    __shared__ double X[28*28];
    __shared__ unsigned int redu[256];
    const int b = blockIdx.x;
    const int t = threadIdx.x;
    const float* xb = x + (size_t)b * 784;
    for (int i = t; i < 784; i += 256) X[i] = (double)xb[i];
    const int c = t & 63;
    const int grp = t >> 6;          // 4 groups x 3 pooled rows
    double w[25];
#pragma unroll
    for (int k = 0; k < 25; ++k) w[k] = (w1[c*25 + k] >= 0.f) ? 1.0 : -1.0;
    const double bias = (double)b1c[c];
    const bool gpos = (g1[c] >= 0.f);
    __syncthreads();

    unsigned int mycnt = 0;
    for (int pr = grp*3; pr < grp*3 + 3; ++pr) {
        unsigned int rowbits = 0;
        for (int pc = 0; pc < 12; ++pc) {
            int nplus = 0;
#pragma unroll
            for (int d = 0; d < 4; ++d) {
                const int i = pr*2 + (d >> 1);
                const int j = pc*2 + (d & 1);
                double acc = 0.0;
#pragma unroll
                for (int ki = 0; ki < 5; ++ki)
#pragma unroll
                    for (int kj = 0; kj < 5; ++kj)
                        acc = fma(w[ki*5 + kj], X[(i+ki)*28 + (j+kj)], acc);
                acc += bias;
                if (acc >= 0.0) ++nplus;
            }
            mycnt += (unsigned int)nplus;
            const bool s = gpos ? (nplus > 0) : (nplus < 4);
            rowbits |= (s ? 1u : 0u) << pc;
        }
        s1p[((size_t)b*64 + c)*12 + pr] = (unsigned short)rowbits;
    }
    redu[t] = mycnt;
    __syncthreads();
    if (t < 64) {
        unsigned int v = redu[t] + redu[t+64] + redu[t+128] + redu[t+192];
        atomicAdd(&cnt1[t], v);
    }
}

// ---------------------------------------------------------------- k2: consts1
__global__ __launch_bounds__(256) void k2_consts1(
    const float* __restrict__ w2, const float* __restrict__ b2c,
    const float* __restrict__ g1, const float* __restrict__ b1bn,
    const unsigned int* __restrict__ cnt1,
    double* __restrict__ alpha1, double* __restrict__ beta1,
    unsigned int* __restrict__ W2bits, double* __restrict__ C2)
{
    const int t = threadIdx.x;
    const double N1 = 4096.0 * 576.0;
    if (t < 64) {
        double m = (2.0 * (double)cnt1[t] - N1) / N1;
        double r = 1.0 / sqrt((1.0 - m*m) + EPSD);
        double g = (double)g1[t];
        alpha1[t] = (double)b1bn[t] - m * r * g;
        beta1[t]  = fabs(g) * r;
    }
    for (int e = t; e < 96*64; e += 256) {
        const float* wp = w2 + (size_t)e * 25;
        unsigned int bits = 0;
#pragma unroll
        for (int k = 0; k < 25; ++k) bits |= (wp[k] >= 0.f ? 1u : 0u) << k;
        W2bits[e] = bits;
    }
    __syncthreads();
    if (t < 96) {
        double s = (double)b2c[t];
        for (int c = 0; c < 64; ++c) {
            const float* wp = w2 + ((size_t)t*64 + c) * 25;
            double sw = 0.0;
#pragma unroll
            for (int k = 0; k < 25; ++k) sw += (wp[k] >= 0.f) ? 1.0 : -1.0;
            s += sw * alpha1[c];
        }
        C2[t] = s;
    }
}

// ---------------------------------------------------------------- k3: conv2
__global__ __launch_bounds__(384) void k3_conv2(
    const unsigned short* __restrict__ s1p, const unsigned int* __restrict__ W2bits,
    const double* __restrict__ beta1, const double* __restrict__ C2,
    const float* __restrict__ g2, signed char* __restrict__ s2,
    unsigned int* __restrict__ cnt2)
{
    __shared__ unsigned short S[64*12];
    __shared__ unsigned int WB[96*64];
    __shared__ unsigned int red[384];
    const int b = blockIdx.x;
    const int t = threadIdx.x;
    const unsigned short* sp = s1p + (size_t)b * 768;
    for (int i = t; i < 768; i += 384) S[i] = sp[i];
    for (int i = t; i < 6144; i += 384) WB[i] = W2bits[i];
    __syncthreads();

    const int o = t % 96;
    const int grp = t / 96;          // 4 groups x 2 output rows
    const int r0 = grp * 2;
    double z[16];
#pragma unroll
    for (int i = 0; i < 16; ++i) z[i] = 0.0;

    for (int c = 0; c < 64; ++c) {
        const unsigned int wb = WB[o*64 + c];
        const unsigned short* sr = &S[c*12];
        int mis[16];
#pragma unroll
        for (int i = 0; i < 16; ++i) mis[i] = 0;
#pragma unroll
        for (int ki = 0; ki < 5; ++ki) {
            const unsigned int wrow = (wb >> (5*ki)) & 31u;
            const unsigned int sa = sr[r0 + ki];
            const unsigned int sb = sr[r0 + 1 + ki];
#pragma unroll
            for (int j = 0; j < 8; ++j) {
                mis[j]     += __popc(((sa >> j) & 31u) ^ wrow);
                mis[8 + j] += __popc(((sb >> j) & 31u) ^ wrow);
            }
        }
        const double bc = beta1[c];
#pragma unroll
        for (int i = 0; i < 16; ++i)
            z[i] = fma(bc, (double)(25 - 2*mis[i]), z[i]);
    }
    const double c2 = C2[o];
    unsigned int tb = 0;
#pragma unroll
    for (int i = 0; i < 16; ++i) tb |= ((z[i] + c2) >= 0.0 ? 1u : 0u) << i;
    red[t] = (unsigned int)__popc(tb);

    const bool gp = (g2[o] >= 0.f);
    const size_t fbase = (size_t)b*1536 + (size_t)o*16 + (size_t)grp*4;
#pragma unroll
    for (int pj = 0; pj < 4; ++pj) {
        unsigned int four = ((tb >> (2*pj)) & 3u) | (((tb >> (8 + 2*pj)) & 3u) << 2);
        bool s = gp ? (four != 0u) : (four != 15u);
        s2[fbase + pj] = s ? (signed char)1 : (signed char)-1;
    }
    __syncthreads();
    if (t < 96) {
        unsigned int v = red[t] + red[t+96] + red[t+192] + red[t+288];
        atomicAdd(&cnt2[t], v);
    }
}

// ---------------------------------------------------------------- k4a: bn2 consts
__global__ __launch_bounds__(128) void k4a_consts2(
    const unsigned int* __restrict__ cnt2, const float* __restrict__ g2,
    const float* __restrict__ b2bn, double* __restrict__ alpha2,
    double* __restrict__ beta2)
{
    const int o = threadIdx.x;
    if (o < 96) {
        const double N2 = 4096.0 * 64.0;
        double m = (2.0 * (double)cnt2[o] - N2) / N2;
        double r = 1.0 / sqrt((1.0 - m*m) + EPSD);
        double g = (double)g2[o];
        alpha2[o] = (double)b2bn[o] - m * r * g;
        beta2[o]  = fabs(g) * r;
    }
}

// ---------------------------------------------------------------- k4b: bn3 consts
__global__ __launch_bounds__(256) void k4b_bn3(
    const signed char* __restrict__ s2, const double* __restrict__ alpha2,
    const double* __restrict__ beta2, const float* __restrict__ g3,
    const float* __restrict__ b3bn, double* __restrict__ A3, double* __restrict__ B3)
{
    const int f = blockIdx.x * 256 + threadIdx.x;   // < 1536
    int sum = 0;
#pragma unroll 8
    for (int b = 0; b < 4096; ++b) sum += (int)s2[(size_t)b*1536 + f];
    const double ms = (double)sum / 4096.0;
    const int c = f >> 4;
    const double b2v = beta2[c];
    const double var = b2v*b2v*(1.0 - ms*ms);
    const double r = 1.0 / sqrt(var + EPSD);
    const double g = (double)g3[f];
    A3[f] = (double)b3bn[f] - b2v * ms * r * g;
    B3[f] = b2v * r * g;
    (void)alpha2;
}

// ---------------------------------------------------------------- k5: fc1 offsets
__global__ __launch_bounds__(256) void k5_c1j(
    const float* __restrict__ fc1w, const float* __restrict__ fc1b,
    const double* __restrict__ A3, double* __restrict__ c1j)
{
    const int j = blockIdx.x * 256 + threadIdx.x;   // < 1024
    const float* wr = fc1w + (size_t)j * 1536;
    double acc = (double)fc1b[j];
    for (int f = 0; f < 1536; ++f)
        acc += (wr[f] >= 0.f) ? A3[f] : -A3[f];
    c1j[j] = acc;
}

// ---------------------------------------------------------------- k6: fc1 GEMM
__global__ __launch_bounds__(256) void k6_fc1(
    const signed char* __restrict__ s2, const float* __restrict__ fc1w,
    const double* __restrict__ B3, const double* __restrict__ c1j,
    signed char* __restrict__ t4)
{
    __shared__ signed char sS[64][64];
    __shared__ signed char sW[64][64];
    __shared__ double sB[64];
    const int bx = blockIdx.x & 63;        // b tile
    const int by = blockIdx.x >> 6;        // j tile (0..15)
    const int b0 = bx * 64, j0 = by * 64;
    const int t = threadIdx.x;
    const int tb = t & 15, tj = t >> 4;
    double acc[4][4];
#pragma unroll
    for (int a = 0; a < 4; ++a)
#pragma unroll
        for (int bq = 0; bq < 4; ++bq) acc[a][bq] = 0.0;

    const int row = t >> 2, seg = t & 3;
    for (int fc = 0; fc < 1536; fc += 64) {
        __syncthreads();
        // stage s2 tile (64 rows x 64 bytes)
        {
            const int4* src = (const int4*)(s2 + (size_t)(b0 + row)*1536 + fc + seg*16);
            *(int4*)(&sS[row][seg*16]) = *src;
        }
        // stage fc1_w sign tile
        {
            const float4* src = (const float4*)(fc1w + (size_t)(j0 + row)*1536 + fc + seg*16);
            unsigned int words[4];
#pragma unroll
            for (int q = 0; q < 4; ++q) {
                float4 v = src[q];
                unsigned int r = (unsigned int)(unsigned char)(v.x >= 0.f ? 1 : -1);
                r |= ((unsigned int)(unsigned char)(v.y >= 0.f ? 1 : -1)) << 8;
                r |= ((unsigned int)(unsigned char)(v.z >= 0.f ? 1 : -1)) << 16;
                r |= ((unsigned int)(unsigned char)(v.w >= 0.f ? 1 : -1)) << 24;
                words[q] = r;
            }
            uint4 wv = make_uint4(words[0], words[1], words[2], words[3]);
            *(uint4*)(&sW[row][seg*16]) = wv;
        }
        if (t < 64) sB[t] = B3[fc + t];
        __syncthreads();

        for (int ff = 0; ff < 64; ++ff) {
            const double bv = sB[ff];
            double sv[4];
#pragma unroll
            for (int ib = 0; ib < 4; ++ib)
                sv[ib] = (sS[tb + 16*ib][ff] > 0) ? bv : -bv;
#pragma unroll
            for (int ij = 0; ij < 4; ++ij) {
                const bool wp = (sW[tj + 16*ij][ff] > 0);
#pragma unroll
                for (int ib = 0; ib < 4; ++ib)
                    acc[ib][ij] += wp ? sv[ib] : -sv[ib];
            }
        }
    }
#pragma unroll
    for (int ib = 0; ib < 4; ++ib)
#pragma unroll
        for (int ij = 0; ij < 4; ++ij) {
            const int b = b0 + tb + 16*ib;
            const int j = j0 + tj + 16*ij;
            const double p = acc[ib][ij] + c1j[j];
            t4[(size_t)b*1024 + j] = (p >= 0.0) ? (signed char)1 : (signed char)-1;
        }
}

// ---------------------------------------------------------------- k7: bn4 + fc2 consts
__global__ __launch_bounds__(1024) void k7_bn4(
    const signed char* __restrict__ t4, const float* __restrict__ g4,
    const float* __restrict__ b4bn, const float* __restrict__ fc2w,
    const float* __restrict__ fc2b, double* __restrict__ A4,
    double* __restrict__ B4, double* __restrict__ C3)
{
    const int j = threadIdx.x;
    int sum = 0;
#pragma unroll 8
    for (int b = 0; b < 4096; ++b) sum += (int)t4[(size_t)b*1024 + j];
    const double m = (double)sum / 4096.0;
    const double r = 1.0 / sqrt((1.0 - m*m) + EPSD);
    const double g = (double)g4[j];
    A4[j] = (double)b4bn[j] - m * r * g;
    B4[j] = r * g;
    __syncthreads();
    if (j < 10) {
        const float* wr = fc2w + (size_t)j * 1024;
        double acc = (double)fc2b[j];
        for (int jj = 0; jj < 1024; ++jj)
            acc += (wr[jj] >= 0.f) ? A4[jj] : -A4[jj];
        C3[j] = acc;
    }
}

// ---------------------------------------------------------------- k8: fc2
__global__ __launch_bounds__(256) void k8_fc2(
    const signed char* __restrict__ t4, const float* __restrict__ fc2w,
    const double* __restrict__ B4, const double* __restrict__ C3,
    float* __restrict__ out)
{
    const int gt = blockIdx.x * 256 + threadIdx.x;   // 40960
    const int b = gt / 10, k = gt % 10;
    const signed char* tr = t4 + (size_t)b * 1024;
    const float* wr = fc2w + (size_t)k * 1024;
    double acc = C3[k];
    for (int j = 0; j < 1024; ++j) {
        const double wb = (wr[j] >= 0.f) ? B4[j] : -B4[j];
        acc = fma(wb, (double)tr[j], acc);
    }
    out[gt] = (float)acc;
}

// ---------------------------------------------------------------- launcher
extern "C" void kernel_launch(void* const* d_in, const int* in_sizes, int n_in,
                              void* d_out, int out_size, void* d_ws, size_t ws_size,
                              hipStream_t stream)
{
    const float* x    = (const float*)d_in[0];
    const float* w1   = (const float*)d_in[1];
    const float* b1c  = (const float*)d_in[2];
    const float* g1   = (const float*)d_in[3];
    const float* b1bn = (const float*)d_in[4];
    const float* w2   = (const float*)d_in[5];
    const float* b2c  = (const float*)d_in[6];
    const float* g2   = (const float*)d_in[7];
    const float* b2bn = (const float*)d_in[8];
    const float* g3   = (const float*)d_in[9];
    const float* b3bn = (const float*)d_in[10];
    const float* fw1  = (const float*)d_in[11];
    const float* fb1  = (const float*)d_in[12];
    const float* g4   = (const float*)d_in[13];
    const float* b4bn = (const float*)d_in[14];
    const float* fw2  = (const float*)d_in[15];
    const float* fb2  = (const float*)d_in[16];

    char* ws = (char*)d_ws;
    unsigned int* cnt1   = (unsigned int*)(ws + O_CNT1);
    unsigned int* cnt2   = (unsigned int*)(ws + O_CNT2);
    double* alpha1       = (double*)(ws + O_ALPHA1);
    double* beta1        = (double*)(ws + O_BETA1);
    double* C2           = (double*)(ws + O_C2);
    double* alpha2       = (double*)(ws + O_ALPHA2);
    double* beta2        = (double*)(ws + O_BETA2);
    double* A3           = (double*)(ws + O_A3);
    double* B3           = (double*)(ws + O_B3);
    double* c1j          = (double*)(ws + O_C1J);
    double* A4           = (double*)(ws + O_A4);
    double* B4           = (double*)(ws + O_B4);
    double* C3           = (double*)(ws + O_C3);
    unsigned int* W2bits = (unsigned int*)(ws + O_W2BITS);
    unsigned short* s1p  = (unsigned short*)(ws + O_S1P);
    signed char* s2      = (signed char*)(ws + O_S2);
    signed char* t4      = (signed char*)(ws + O_T4);

    hipMemsetAsync(ws, 0, 1024, stream);
    k1_conv1<<<4096, 256, 0, stream>>>(x, w1, b1c, g1, s1p, cnt1);
    k2_consts1<<<1, 256, 0, stream>>>(w2, b2c, g1, b1bn, cnt1, alpha1, beta1, W2bits, C2);
    k3_conv2<<<4096, 384, 0, stream>>>(s1p, W2bits, beta1, C2, g2, s2, cnt2);
    k4a_consts2<<<1, 128, 0, stream>>>(cnt2, g2, b2bn, alpha2, beta2);
    k4b_bn3<<<6, 256, 0, stream>>>(s2, alpha2, beta2, g3, b3bn, A3, B3);
    k5_c1j<<<4, 256, 0, stream>>>(fw1, fb1, A3, c1j);
    k6_fc1<<<1024, 256, 0, stream>>>(s2, fw1, B3, c1j, t4);
    k7_bn4<<<1, 1024, 0, stream>>>(t4, g4, b4bn, fw2, fb2, A4, B4, C3);
    k8_fc2<<<160, 256, 0, stream>>>(t4, fw2, B4, C3, (float*)d_out);

    (void)in_sizes; (void)n_in; (void)out_size; (void)ws_size;
}

// Round 2
// 1784.515 us; speedup vs baseline: 1.1822x; 1.1822x over previous
//
#include <hip/hip_runtime.h>
#include <hip/hip_bf16.h>
#include <math.h>

// Binarized ConvNet, exact-sign implementation (round 2).
//  k1 : conv1 f64 -> pooled sign bits s1p + cnt1
//  k2a: bn1 constants     k2b: W2 sign bits (transposed [c][o])   k2c: C2 offsets
//  k3 : conv2 XOR-popcount + f64 combine -> s2 (+cnt2)   [bank-conflict-free WB]
//  k4a: bn2 consts   k4ba: s2 column sums (packed)   k4bb: A3,B3
//  k5w: fc1 weight sign bytes   k5: fc1 offsets c1j (wave/j)
//  k6 : fc1 f64 xor-sign GEMM -> t4
//  k7a: t4 column sums (packed)   k7b: A4,B4,C3
//  k8 : fc2 (wave/output, f64)

static const double EPSD = 1e-5;

// ---------------- ws layout (bytes) ----------------
#define O_CNT1   0          // 64 u32
#define O_CNT2   256        // 96 u32
#define O_CS3    1024       // 1536 i32
#define O_CS4    7168       // 1024 i32
#define ZERO_BYTES 11264
#define O_ALPHA1 11264      // 64 f64
#define O_BETA1  11776
#define O_C2     12288      // 96 f64
#define O_ALPHA2 13056
#define O_BETA2  13824
#define O_A3     14592      // 1536 f64
#define O_B3     26880
#define O_C1J    39168      // 1024 f64
#define O_A4     47360
#define O_B4     55552
#define O_C3     63744      // 10 f64
#define O_W2BITS 65536      // 6144 u32 [c][o]
#define O_S1P    131072     // 4096*64*12 u16 (dead after k3; reused for w1s)
#define O_W1S    131072     // 1024*1536 i8 sign bytes (written after k3)
#define O_S2     6422528    // 4096*1536 i8
#define O_T4     12713984   // 4096*1024 i8

// ---------------------------------------------------------------- k1: conv1
__global__ __launch_bounds__(256) void k1_conv1(
    const float* __restrict__ x, const float* __restrict__ w1,
    const float* __restrict__ b1c, const float* __restrict__ g1,
    unsigned short* __restrict__ s1p, unsigned int* __restrict__ cnt1)
{
    __shared__ double X[28*28];
    __shared__ unsigned int redu[256];
    const int b = blockIdx.x;
    const int t = threadIdx.x;
    const float* xb = x + (size_t)b * 784;
    for (int i = t; i < 784; i += 256) X[i] = (double)xb[i];
    const int c = t & 63;
    const int grp = t >> 6;          // 4 groups x 3 pooled rows
    double w[25];
#pragma unroll
    for (int k = 0; k < 25; ++k) w[k] = (w1[c*25 + k] >= 0.f) ? 1.0 : -1.0;
    const double bias = (double)b1c[c];
    const bool gpos = (g1[c] >= 0.f);
    __syncthreads();

    unsigned int mycnt = 0;
    for (int pr = grp*3; pr < grp*3 + 3; ++pr) {
        unsigned int rowbits = 0;
        for (int pc = 0; pc < 12; ++pc) {
            int nplus = 0;
#pragma unroll
            for (int d = 0; d < 4; ++d) {
                const int i = pr*2 + (d >> 1);
                const int j = pc*2 + (d & 1);
                double acc = 0.0;
#pragma unroll
                for (int ki = 0; ki < 5; ++ki)
#pragma unroll
                    for (int kj = 0; kj < 5; ++kj)
                        acc = fma(w[ki*5 + kj], X[(i+ki)*28 + (j+kj)], acc);
                acc += bias;
                if (acc >= 0.0) ++nplus;
            }
            mycnt += (unsigned int)nplus;
            const bool s = gpos ? (nplus > 0) : (nplus < 4);
            rowbits |= (s ? 1u : 0u) << pc;
        }
        s1p[((size_t)b*64 + c)*12 + pr] = (unsigned short)rowbits;
    }
    redu[t] = mycnt;
    __syncthreads();
    if (t < 64) {
        unsigned int v = redu[t] + redu[t+64] + redu[t+128] + redu[t+192];
        atomicAdd(&cnt1[t], v);
    }
}

// ---------------------------------------------------------------- k2a: bn1 consts
__global__ __launch_bounds__(64) void k2a_consts1(
    const float* __restrict__ g1, const float* __restrict__ b1bn,
    const unsigned int* __restrict__ cnt1,
    double* __restrict__ alpha1, double* __restrict__ beta1)
{
    const int t = threadIdx.x;
    const double N1 = 4096.0 * 576.0;
    double m = (2.0 * (double)cnt1[t] - N1) / N1;
    double r = 1.0 / sqrt((1.0 - m*m) + EPSD);
    double g = (double)g1[t];
    alpha1[t] = (double)b1bn[t] - m * r * g;
    beta1[t]  = fabs(g) * r;
}

// ---------------------------------------------------------------- k2b: W2 bits (transposed)
__global__ __launch_bounds__(256) void k2b_w2bits(
    const float* __restrict__ w2, unsigned int* __restrict__ W2bits)
{
    const int e = blockIdx.x * 256 + threadIdx.x;   // < 6144, e = o*64+c
    const int o = e >> 6, c = e & 63;
    const float* wp = w2 + (size_t)e * 25;
    unsigned int bits = 0;
#pragma unroll
    for (int k = 0; k < 25; ++k) bits |= (wp[k] >= 0.f ? 1u : 0u) << k;
    W2bits[c*96 + o] = bits;
}

// ---------------------------------------------------------------- k2c: C2 offsets
__global__ __launch_bounds__(64) void k2c_c2(
    const float* __restrict__ w2, const float* __restrict__ b2c,
    const double* __restrict__ alpha1, double* __restrict__ C2)
{
    const int o = blockIdx.x;        // 96 blocks, 64 lanes
    const int c = threadIdx.x;
    const float* wp = w2 + ((size_t)o*64 + c) * 25;
    double sw = 0.0;
#pragma unroll
    for (int k = 0; k < 25; ++k) sw += (wp[k] >= 0.f) ? 1.0 : -1.0;
    double part = sw * alpha1[c];
#pragma unroll
    for (int off = 32; off; off >>= 1) part += __shfl_down(part, off);
    if (c == 0) C2[o] = part + (double)b2c[o];
}

// ---------------------------------------------------------------- k3: conv2
__global__ __launch_bounds__(384) void k3_conv2(
    const unsigned short* __restrict__ s1p, const unsigned int* __restrict__ W2bits,
    const double* __restrict__ beta1, const double* __restrict__ C2,
    const float* __restrict__ g2, signed char* __restrict__ s2,
    unsigned int* __restrict__ cnt2)
{
    __shared__ unsigned int S32[64*6];       // 64 ch x 12 u16 rows, as u32
    __shared__ unsigned int WB[64*96];       // [c][o] -> conflict-free reads
    __shared__ unsigned int red[384];
    const int b = blockIdx.x;
    const int t = threadIdx.x;
    const unsigned int* sp32 = (const unsigned int*)(s1p + (size_t)b * 768);
    S32[t] = sp32[t];                        // 384 u32
    for (int i = t; i < 6144; i += 384) WB[i] = W2bits[i];
    __syncthreads();

    const int o = t % 96;
    const int grp = t / 96;                  // 4 groups x 2 output rows
    double z[16];
#pragma unroll
    for (int i = 0; i < 16; ++i) z[i] = 0.0;

    for (int c = 0; c < 64; ++c) {
        const unsigned int wb = WB[c*96 + o];            // lane-consecutive
        const unsigned int d0 = S32[c*6 + grp];
        const unsigned int d1 = S32[c*6 + grp + 1];
        const unsigned int d2 = S32[c*6 + grp + 2];
        unsigned int rows[6];
        rows[0] = d0 & 0xFFFFu; rows[1] = d0 >> 16;
        rows[2] = d1 & 0xFFFFu; rows[3] = d1 >> 16;
        rows[4] = d2 & 0xFFFFu; rows[5] = d2 >> 16;
        int mis[16];
#pragma unroll
        for (int i = 0; i < 16; ++i) mis[i] = 0;
#pragma unroll
        for (int ki = 0; ki < 5; ++ki) {
            const unsigned int wrow = (wb >> (5*ki)) & 31u;
            const unsigned int sa = rows[ki];
            const unsigned int sb = rows[ki + 1];
#pragma unroll
            for (int j = 0; j < 8; ++j) {
                mis[j]     += __popc(((sa >> j) & 31u) ^ wrow);
                mis[8 + j] += __popc(((sb >> j) & 31u) ^ wrow);
            }
        }
        const double bc = beta1[c];
#pragma unroll
        for (int i = 0; i < 16; ++i)
            z[i] = fma(bc, (double)(25 - 2*mis[i]), z[i]);
    }
    const double c2 = C2[o];
    unsigned int tb = 0;
#pragma unroll
    for (int i = 0; i < 16; ++i) tb |= ((z[i] + c2) >= 0.0 ? 1u : 0u) << i;
    red[t] = (unsigned int)__popc(tb);

    const bool gp = (g2[o] >= 0.f);
    const size_t fbase = (size_t)b*1536 + (size_t)o*16 + (size_t)grp*4;
#pragma unroll
    for (int pj = 0; pj < 4; ++pj) {
        unsigned int four = ((tb >> (2*pj)) & 3u) | (((tb >> (8 + 2*pj)) & 3u) << 2);
        bool s = gp ? (four != 0u) : (four != 15u);
        s2[fbase + pj] = s ? (signed char)1 : (signed char)-1;
    }
    __syncthreads();
    if (t < 96) {
        unsigned int v = red[t] + red[t+96] + red[t+192] + red[t+288];
        atomicAdd(&cnt2[t], v);
    }
}

// ---------------------------------------------------------------- k4a: bn2 consts
__global__ __launch_bounds__(128) void k4a_consts2(
    const unsigned int* __restrict__ cnt2, const float* __restrict__ g2,
    const float* __restrict__ b2bn, double* __restrict__ alpha2,
    double* __restrict__ beta2)
{
    const int o = threadIdx.x;
    if (o < 96) {
        const double N2 = 4096.0 * 64.0;
        double m = (2.0 * (double)cnt2[o] - N2) / N2;
        double r = 1.0 / sqrt((1.0 - m*m) + EPSD);
        double g = (double)g2[o];
        alpha2[o] = (double)b2bn[o] - m * r * g;
        beta2[o]  = fabs(g) * r;
    }
}

// ---------------------------------------------------------------- k4ba: s2 column sums
__global__ __launch_bounds__(384) void k4ba_colsum3(
    const signed char* __restrict__ s2, int* __restrict__ cs3)
{
    const int t = threadIdx.x;
    const int seg = t % 96, rowg = t / 96;          // 96 segs x 16B, 4 row groups
    const int b0 = blockIdx.x * 32;
    unsigned int am0 = 0, am1 = 0, am2 = 0, am3 = 0; // packed per-byte minus counts
#pragma unroll
    for (int k = 0; k < 8; ++k) {
        const int b = b0 + rowg*8 + k;
        const uint4 v = *(const uint4*)(s2 + (size_t)b*1536 + seg*16);
        am0 += (v.x >> 1) & 0x01010101u;
        am1 += (v.y >> 1) & 0x01010101u;
        am2 += (v.z >> 1) & 0x01010101u;
        am3 += (v.w >> 1) & 0x01010101u;
    }
    __shared__ unsigned int sm[384][4];
    sm[t][0] = am0; sm[t][1] = am1; sm[t][2] = am2; sm[t][3] = am3;
    __syncthreads();
    if (t < 96) {
#pragma unroll
        for (int d = 0; d < 4; ++d) {
            unsigned int m = sm[t][d] + sm[t+96][d] + sm[t+192][d] + sm[t+288][d];
#pragma unroll
            for (int bb = 0; bb < 4; ++bb) {
                int minus = (int)((m >> (8*bb)) & 0xFFu);
                atomicAdd(&cs3[t*16 + d*4 + bb], 32 - 2*minus);
            }
        }
    }
}

// ---------------------------------------------------------------- k4bb: A3,B3
__global__ __launch_bounds__(256) void k4bb_bn3(
    const int* __restrict__ cs3, const double* __restrict__ beta2,
    const float* __restrict__ g3, const float* __restrict__ b3bn,
    double* __restrict__ A3, double* __restrict__ B3)
{
    const int f = blockIdx.x * 256 + threadIdx.x;   // < 1536
    const double ms = (double)cs3[f] / 4096.0;
    const int c = f >> 4;
    const double b2v = beta2[c];
    const double var = b2v*b2v*(1.0 - ms*ms);
    const double r = 1.0 / sqrt(var + EPSD);
    const double g = (double)g3[f];
    A3[f] = (double)b3bn[f] - b2v * ms * r * g;
    B3[f] = b2v * r * g;
}

// ---------------------------------------------------------------- k5w: fc1 sign bytes
__global__ __launch_bounds__(256) void k5w_signs(
    const float* __restrict__ fw1, signed char* __restrict__ w1s)
{
    const int idx = blockIdx.x * 256 + threadIdx.x;   // < 393216 float4s
    const float4 v = ((const float4*)fw1)[idx];
    uchar4 o;
    o.x = (v.x >= 0.f) ? 0x01 : 0xFF;
    o.y = (v.y >= 0.f) ? 0x01 : 0xFF;
    o.z = (v.z >= 0.f) ? 0x01 : 0xFF;
    o.w = (v.w >= 0.f) ? 0x01 : 0xFF;
    ((uchar4*)w1s)[idx] = o;
}

// ---------------------------------------------------------------- k5: fc1 offsets (wave/j)
__global__ __launch_bounds__(256) void k5_c1j(
    const signed char* __restrict__ w1s, const float* __restrict__ fc1b,
    const double* __restrict__ A3, double* __restrict__ c1j)
{
    const int t = threadIdx.x;
    const int lane = t & 63, w = t >> 6;
    const int j = blockIdx.x * 4 + w;                 // grid 256
    double acc = 0.0;
#pragma unroll
    for (int q = 0; q < 6; ++q) {
        const int f0 = q*256 + lane*4;
        const unsigned int wb = *(const unsigned int*)(w1s + (size_t)j*1536 + f0);
#pragma unroll
        for (int bb = 0; bb < 4; ++bb) {
            const double a = A3[f0 + bb];
            acc += ((wb >> (8*bb)) & 0x80u) ? -a : a;
        }
    }
#pragma unroll
    for (int off = 32; off; off >>= 1) acc += __shfl_down(acc, off);
    if (lane == 0) c1j[j] = acc + (double)fc1b[j];
}

// ---------------------------------------------------------------- k6: fc1 GEMM
__global__ __launch_bounds__(256) void k6_fc1(
    const signed char* __restrict__ s2, const signed char* __restrict__ w1s,
    const double* __restrict__ B3, const double* __restrict__ c1j,
    signed char* __restrict__ t4)
{
    __shared__ signed char sS[64][80];     // stride 80B: 16B-aligned, 2-way banks
    __shared__ signed char sW[64][80];
    __shared__ double sB[64];
    const int bx = blockIdx.x & 63;        // b tile
    const int by = blockIdx.x >> 6;        // j tile
    const int b0 = bx * 64, j0 = by * 64;
    const int t = threadIdx.x;
    const int tb = t & 15, tj = t >> 4;
    double acc[4][4];
#pragma unroll
    for (int a = 0; a < 4; ++a)
#pragma unroll
        for (int bq = 0; bq < 4; ++bq) acc[a][bq] = 0.0;

    const int row = t >> 2, seg = t & 3;
    for (int fc = 0; fc < 1536; fc += 64) {
        __syncthreads();
        *(int4*)(&sS[row][seg*16]) = *(const int4*)(s2 + (size_t)(b0+row)*1536 + fc + seg*16);
        *(int4*)(&sW[row][seg*16]) = *(const int4*)(w1s + (size_t)(j0+row)*1536 + fc + seg*16);
        if (t < 64) sB[t] = B3[fc + t];
        __syncthreads();

        for (int f4 = 0; f4 < 64; f4 += 4) {
            unsigned int sa[4], wa[4];
#pragma unroll
            for (int ib = 0; ib < 4; ++ib)
                sa[ib] = *(const unsigned int*)(&sS[tb + 16*ib][f4]);
#pragma unroll
            for (int ij = 0; ij < 4; ++ij)
                wa[ij] = *(const unsigned int*)(&sW[tj + 16*ij][f4]);
#pragma unroll
            for (int u = 0; u < 4; ++u) {
                const long long bvb = __double_as_longlong(sB[f4 + u]);
                long long sv[4];
#pragma unroll
                for (int ib = 0; ib < 4; ++ib)
                    sv[ib] = bvb ^ ((long long)((sa[ib] >> (8*u+7)) & 1u) << 63);
#pragma unroll
                for (int ij = 0; ij < 4; ++ij) {
                    const long long wm = (long long)((wa[ij] >> (8*u+7)) & 1u) << 63;
#pragma unroll
                    for (int ib = 0; ib < 4; ++ib)
                        acc[ib][ij] += __longlong_as_double(sv[ib] ^ wm);
                }
            }
        }
    }
#pragma unroll
    for (int ib = 0; ib < 4; ++ib)
#pragma unroll
        for (int ij = 0; ij < 4; ++ij) {
            const int b = b0 + tb + 16*ib;
            const int j = j0 + tj + 16*ij;
            const double p = acc[ib][ij] + c1j[j];
            t4[(size_t)b*1024 + j] = (p >= 0.0) ? (signed char)1 : (signed char)-1;
        }
}

// ---------------------------------------------------------------- k7a: t4 column sums
__global__ __launch_bounds__(256) void k7a_colsum4(
    const signed char* __restrict__ t4, int* __restrict__ cs4)
{
    const int t = threadIdx.x;
    const int seg = t & 63, rowg = t >> 6;
    const int b0 = blockIdx.x * 32;
    unsigned int am0 = 0, am1 = 0, am2 = 0, am3 = 0;
#pragma unroll
    for (int k = 0; k < 8; ++k) {
        const int b = b0 + rowg*8 + k;
        const uint4 v = *(const uint4*)(t4 + (size_t)b*1024 + seg*16);
        am0 += (v.x >> 1) & 0x01010101u;
        am1 += (v.y >> 1) & 0x01010101u;
        am2 += (v.z >> 1) & 0x01010101u;
        am3 += (v.w >> 1) & 0x01010101u;
    }
    __shared__ unsigned int sm[256][4];
    sm[t][0] = am0; sm[t][1] = am1; sm[t][2] = am2; sm[t][3] = am3;
    __syncthreads();
    if (t < 64) {
#pragma unroll
        for (int d = 0; d < 4; ++d) {
            unsigned int m = sm[t][d] + sm[t+64][d] + sm[t+128][d] + sm[t+192][d];
#pragma unroll
            for (int bb = 0; bb < 4; ++bb) {
                int minus = (int)((m >> (8*bb)) & 0xFFu);
                atomicAdd(&cs4[t*16 + d*4 + bb], 32 - 2*minus);
            }
        }
    }
}

// ---------------------------------------------------------------- k7b: A4,B4,C3
__global__ __launch_bounds__(1024) void k7b_bn4(
    const int* __restrict__ cs4, const float* __restrict__ g4,
    const float* __restrict__ b4bn, const float* __restrict__ fc2w,
    const float* __restrict__ fc2b, double* __restrict__ A4,
    double* __restrict__ B4, double* __restrict__ C3)
{
    __shared__ double sA4[1024];
    const int j = threadIdx.x;
    const double m = (double)cs4[j] / 4096.0;
    const double r = 1.0 / sqrt((1.0 - m*m) + EPSD);
    const double g = (double)g4[j];
    const double a4 = (double)b4bn[j] - m * r * g;
    A4[j] = a4;
    B4[j] = r * g;
    sA4[j] = a4;
    __syncthreads();
    if (j < 10) {
        const float* wr = fc2w + (size_t)j * 1024;
        double acc = (double)fc2b[j];
        for (int jj = 0; jj < 1024; ++jj)
            acc += (wr[jj] >= 0.f) ? sA4[jj] : -sA4[jj];
        C3[j] = acc;
    }
}

// ---------------------------------------------------------------- k8: fc2 (wave/output)
__global__ __launch_bounds__(256) void k8_fc2(
    const signed char* __restrict__ t4, const float* __restrict__ fc2w,
    const double* __restrict__ B4, const double* __restrict__ C3,
    float* __restrict__ out)
{
    const int t = threadIdx.x;
    const int lane = t & 63;
    const int wv = blockIdx.x * 4 + (t >> 6);        // < 40960
    const int b = wv / 10, kk = wv - b*10;
    const float* wr = fc2w + (size_t)kk * 1024;
    const signed char* tr = t4 + (size_t)b * 1024;
    double acc = 0.0;
#pragma unroll
    for (int q = 0; q < 4; ++q) {
        const int f0 = q*256 + lane*4;
        const float4 w4 = *(const float4*)(wr + f0);
        const unsigned int t4b = *(const unsigned int*)(tr + f0);
        const float wf[4] = {w4.x, w4.y, w4.z, w4.w};
#pragma unroll
        for (int bb = 0; bb < 4; ++bb) {
            const bool ws = (wf[bb] >= 0.f);
            const bool ts = ((t4b >> (8*bb)) & 0x80u) == 0;   // byte +1 ?
            const double bv = B4[f0 + bb];
            acc += (ws == ts) ? bv : -bv;
        }
    }
#pragma unroll
    for (int off = 32; off; off >>= 1) acc += __shfl_down(acc, off);
    if (lane == 0) out[b*10 + kk] = (float)(acc + C3[kk]);
}

// ---------------------------------------------------------------- launcher
extern "C" void kernel_launch(void* const* d_in, const int* in_sizes, int n_in,
                              void* d_out, int out_size, void* d_ws, size_t ws_size,
                              hipStream_t stream)
{
    const float* x    = (const float*)d_in[0];
    const float* w1   = (const float*)d_in[1];
    const float* b1c  = (const float*)d_in[2];
    const float* g1   = (const float*)d_in[3];
    const float* b1bn = (const float*)d_in[4];
    const float* w2   = (const float*)d_in[5];
    const float* b2c  = (const float*)d_in[6];
    const float* g2   = (const float*)d_in[7];
    const float* b2bn = (const float*)d_in[8];
    const float* g3   = (const float*)d_in[9];
    const float* b3bn = (const float*)d_in[10];
    const float* fw1  = (const float*)d_in[11];
    const float* fb1  = (const float*)d_in[12];
    const float* g4   = (const float*)d_in[13];
    const float* b4bn = (const float*)d_in[14];
    const float* fw2  = (const float*)d_in[15];
    const float* fb2  = (const float*)d_in[16];

    char* ws = (char*)d_ws;
    unsigned int* cnt1   = (unsigned int*)(ws + O_CNT1);
    unsigned int* cnt2   = (unsigned int*)(ws + O_CNT2);
    int* cs3             = (int*)(ws + O_CS3);
    int* cs4             = (int*)(ws + O_CS4);
    double* alpha1       = (double*)(ws + O_ALPHA1);
    double* beta1        = (double*)(ws + O_BETA1);
    double* C2           = (double*)(ws + O_C2);
    double* alpha2       = (double*)(ws + O_ALPHA2);
    double* beta2        = (double*)(ws + O_BETA2);
    double* A3           = (double*)(ws + O_A3);
    double* B3           = (double*)(ws + O_B3);
    double* c1j          = (double*)(ws + O_C1J);
    double* A4           = (double*)(ws + O_A4);
    double* B4           = (double*)(ws + O_B4);
    double* C3           = (double*)(ws + O_C3);
    unsigned int* W2bits = (unsigned int*)(ws + O_W2BITS);
    unsigned short* s1p  = (unsigned short*)(ws + O_S1P);
    signed char* w1s     = (signed char*)(ws + O_W1S);
    signed char* s2      = (signed char*)(ws + O_S2);
    signed char* t4      = (signed char*)(ws + O_T4);

    hipMemsetAsync(ws, 0, ZERO_BYTES, stream);
    k1_conv1<<<4096, 256, 0, stream>>>(x, w1, b1c, g1, s1p, cnt1);
    k2a_consts1<<<1, 64, 0, stream>>>(g1, b1bn, cnt1, alpha1, beta1);
    k2b_w2bits<<<24, 256, 0, stream>>>(w2, W2bits);
    k2c_c2<<<96, 64, 0, stream>>>(w2, b2c, alpha1, C2);
    k3_conv2<<<4096, 384, 0, stream>>>(s1p, W2bits, beta1, C2, g2, s2, cnt2);
    k4a_consts2<<<1, 128, 0, stream>>>(cnt2, g2, b2bn, alpha2, beta2);
    k4ba_colsum3<<<128, 384, 0, stream>>>(s2, cs3);
    k4bb_bn3<<<6, 256, 0, stream>>>(cs3, beta2, g3, b3bn, A3, B3);
    k5w_signs<<<1536, 256, 0, stream>>>(fw1, w1s);       // reuses s1p region (dead)
    k5_c1j<<<256, 256, 0, stream>>>(w1s, fb1, A3, c1j);
    k6_fc1<<<1024, 256, 0, stream>>>(s2, w1s, B3, c1j, t4);
    k7a_colsum4<<<128, 256, 0, stream>>>(t4, cs4);
    k7b_bn4<<<1, 1024, 0, stream>>>(cs4, g4, b4bn, fw2, fb2, A4, B4, C3);
    k8_fc2<<<10240, 256, 0, stream>>>(t4, fw2, B4, C3, (float*)d_out);

    (void)in_sizes; (void)n_in; (void)out_size; (void)ws_size; (void)alpha2;
}

// Round 3
// 1465.783 us; speedup vs baseline: 1.4392x; 1.2174x over previous
//
#include <hip/hip_runtime.h>
#include <hip/hip_bf16.h>
#include <math.h>

// Binarized ConvNet, exact-sign implementation (round 3).
//  k1 : conv1 f64, register 6x6 sliding window -> pooled sign bits s1p + cnt1
//  k2a: bn1 constants + sumBeta   k2b: W2 sign bits [c][o]   k2c: C2h thresholds
//  k3 : conv2 via 60-bit packed window XOR-popcount (1 popc64 per output-channel)
//  k4a: bn2 consts   k4ba: s2 column sums   k4bb: A3,B3
//  k5w: fc1 sign bytes   k5: fc1 offsets c1j
//  k6 : fc1 f64 hi-word-xor-sign GEMM -> t4
//  k7a: t4 column sums   k7b: A4,B4,C3
//  k8 : fc2 (wave/output, f64)

static const double EPSD = 1e-5;
typedef unsigned long long u64;

// ---------------- ws layout (bytes) ----------------
#define O_CNT1   0          // 64 u32
#define O_CNT2   256        // 96 u32
#define O_CS3    1024       // 1536 i32
#define O_CS4    7168       // 1024 i32
#define ZERO_BYTES 11264
#define O_ALPHA1 11264      // 64 f64
#define O_BETA1  11776
#define O_C2H    12288      // 96 f64 (threshold form)
#define O_ALPHA2 13056
#define O_BETA2  13824
#define O_A3     14592      // 1536 f64
#define O_B3     26880
#define O_C1J    39168      // 1024 f64
#define O_A4     47360
#define O_B4     55552
#define O_C3     63744      // 10 f64
#define O_SB     64000      // 1 f64 (sum of beta1)
#define O_W2BITS 65536      // 6144 u32 [c][o]
#define O_S1P    131072     // 4096*64*12 u16 (dead after k3; reused for w1s)
#define O_W1S    131072     // 1024*1536 i8 sign bytes
#define O_S2     6422528    // 4096*1536 i8
#define O_T4     12713984   // 4096*1024 i8

// ---------------------------------------------------------------- k1: conv1
__global__ __launch_bounds__(256, 2) void k1_conv1(
    const float* __restrict__ x, const float* __restrict__ w1,
    const float* __restrict__ b1c, const float* __restrict__ g1,
    unsigned short* __restrict__ s1p, unsigned int* __restrict__ cnt1)
{
    __shared__ double X[28*28];
    __shared__ unsigned int redu[256];
    const int b = blockIdx.x;
    const int t = threadIdx.x;
    const float* xb = x + (size_t)b * 784;
    for (int i = t; i < 784; i += 256) X[i] = (double)xb[i];
    const int c = t & 63;
    const int grp = t >> 6;          // 4 groups x 3 pooled rows
    double w[25];
#pragma unroll
    for (int k = 0; k < 25; ++k) w[k] = (w1[c*25 + k] >= 0.f) ? 1.0 : -1.0;
    const double bias = (double)b1c[c];
    const bool gpos = (g1[c] >= 0.f);
    __syncthreads();

    unsigned int mycnt = 0;
    for (int pr = grp*3; pr < grp*3 + 3; ++pr) {
        // 6x6 register window over input rows 2pr..2pr+5, circular in columns
        double win[6][6];
#pragma unroll
        for (int r = 0; r < 6; ++r) {
            const double2* p = (const double2*)&X[(2*pr + r)*28];
            double2 a = p[0], bb = p[1], cc = p[2];
            win[r][0]=a.x; win[r][1]=a.y; win[r][2]=bb.x;
            win[r][3]=bb.y; win[r][4]=cc.x; win[r][5]=cc.y;
        }
        unsigned int rowbits = 0;
#pragma unroll
        for (int pc = 0; pc < 12; ++pc) {
            int nplus = 0;
#pragma unroll
            for (int d = 0; d < 4; ++d) {
                const int d0 = d >> 1, d1 = d & 1;
                double acc = 0.0;
#pragma unroll
                for (int ki = 0; ki < 5; ++ki)
#pragma unroll
                    for (int kj = 0; kj < 5; ++kj)
                        acc = fma(w[ki*5 + kj], win[d0 + ki][(2*pc + d1 + kj) % 6], acc);
                acc += bias;
                if (acc >= 0.0) ++nplus;
            }
            mycnt += (unsigned int)nplus;
            const bool s = gpos ? (nplus > 0) : (nplus < 4);
            rowbits |= (s ? 1u : 0u) << pc;
            if (pc < 11) {
#pragma unroll
                for (int r = 0; r < 6; ++r) {
                    const double2 nv = *(const double2*)&X[(2*pr + r)*28 + 2*pc + 6];
                    win[r][(2*pc + 6) % 6] = nv.x;
                    win[r][(2*pc + 7) % 6] = nv.y;
                }
            }
        }
        s1p[((size_t)b*64 + c)*12 + pr] = (unsigned short)rowbits;
    }
    redu[t] = mycnt;
    __syncthreads();
    if (t < 64) {
        unsigned int v = redu[t] + redu[t+64] + redu[t+128] + redu[t+192];
        atomicAdd(&cnt1[t], v);
    }
}

// ---------------------------------------------------------------- k2a: bn1 consts + sumBeta
__global__ __launch_bounds__(64) void k2a_consts1(
    const float* __restrict__ g1, const float* __restrict__ b1bn,
    const unsigned int* __restrict__ cnt1,
    double* __restrict__ alpha1, double* __restrict__ beta1,
    double* __restrict__ sumBeta)
{
    const int t = threadIdx.x;
    const double N1 = 4096.0 * 576.0;
    double m = (2.0 * (double)cnt1[t] - N1) / N1;
    double r = 1.0 / sqrt((1.0 - m*m) + EPSD);
    double g = (double)g1[t];
    alpha1[t] = (double)b1bn[t] - m * r * g;
    const double bt = fabs(g) * r;
    beta1[t] = bt;
    double s = bt;
#pragma unroll
    for (int off = 32; off; off >>= 1) s += __shfl_down(s, off);
    if (t == 0) sumBeta[0] = s;
}

// ---------------------------------------------------------------- k2b: W2 bits (transposed)
__global__ __launch_bounds__(256) void k2b_w2bits(
    const float* __restrict__ w2, unsigned int* __restrict__ W2bits)
{
    const int e = blockIdx.x * 256 + threadIdx.x;   // < 6144, e = o*64+c
    const int o = e >> 6, c = e & 63;
    const float* wp = w2 + (size_t)e * 25;
    unsigned int bits = 0;
#pragma unroll
    for (int k = 0; k < 25; ++k) bits |= (wp[k] >= 0.f ? 1u : 0u) << k;
    W2bits[c*96 + o] = bits;
}

// ---------------------------------------------------------------- k2c: C2h thresholds
__global__ __launch_bounds__(64) void k2c_c2(
    const float* __restrict__ w2, const float* __restrict__ b2c,
    const double* __restrict__ alpha1, const double* __restrict__ sumBeta,
    double* __restrict__ C2h)
{
    const int o = blockIdx.x;        // 96 blocks, 64 lanes
    const int c = threadIdx.x;
    const float* wp = w2 + ((size_t)o*64 + c) * 25;
    double sw = 0.0;
#pragma unroll
    for (int k = 0; k < 25; ++k) sw += (wp[k] >= 0.f) ? 1.0 : -1.0;
    double part = sw * alpha1[c];
#pragma unroll
    for (int off = 32; off; off >>= 1) part += __shfl_down(part, off);
    if (c == 0) C2h[o] = (part + (double)b2c[o] + 25.0 * sumBeta[0]) * 0.5;
}

// ---------------------------------------------------------------- k3: conv2
__global__ __launch_bounds__(384) void k3_conv2(
    const unsigned short* __restrict__ s1p, const unsigned int* __restrict__ W2bits,
    const double* __restrict__ beta1g, const double* __restrict__ C2h,
    const float* __restrict__ g2, signed char* __restrict__ s2,
    unsigned int* __restrict__ cnt2)
{
    __shared__ unsigned int S32[64*6];       // 64 ch x 12 u16 rows, as u32
    __shared__ unsigned int WB[64*96];       // [c][o]
    __shared__ double sBeta[64];
    __shared__ unsigned int lcnt[96];
    const int b = blockIdx.x;
    const int t = threadIdx.x;
    const unsigned int* sp32 = (const unsigned int*)(s1p + (size_t)b * 768);
    S32[t] = sp32[t];                        // 384 u32
    for (int i = t; i < 6144; i += 384) WB[i] = W2bits[i];
    if (t < 64) sBeta[t] = beta1g[t];
    if (t < 96) lcnt[t] = 0;
    __syncthreads();

    const int o = t % 96;
    const int grp = t / 96;                  // 4 groups x 2 output rows
    const u64 M5 = 0x1FULL | (0x1FULL<<12) | (0x1FULL<<24) | (0x1FULL<<36) | (0x1FULL<<48);
    double zm[16];
#pragma unroll
    for (int i = 0; i < 16; ++i) zm[i] = 0.0;

    for (int c = 0; c < 64; ++c) {
        const unsigned int wb = WB[c*96 + o];
        // spread 25-bit weights to stride-12 lanes
        const u64 wp = (u64)(wb & 31u)
                     | ((u64)((wb >> 5) & 31u) << 12)
                     | ((u64)((wb >> 10) & 31u) << 24)
                     | ((u64)((wb >> 15) & 31u) << 36)
                     | ((u64)((wb >> 20) & 31u) << 48);
        const unsigned int d0 = S32[c*6 + grp];
        const unsigned int d1 = S32[c*6 + grp + 1];
        const unsigned int d2 = S32[c*6 + grp + 2];
        const u64 r0 = d0 & 0xFFFFu, r1 = d0 >> 16;
        const u64 r2 = d1 & 0xFFFFu, r3 = d1 >> 16;
        const u64 r4 = d2 & 0xFFFFu, r5 = d2 >> 16;
        const u64 P0 = r0 | (r1 << 12) | (r2 << 24) | (r3 << 36) | (r4 << 48);
        const u64 P1 = (P0 >> 12) | (r5 << 48);
        const double bc = sBeta[c];
#pragma unroll
        for (int j = 0; j < 8; ++j) {
            const u64 m0 = ((P0 >> j) ^ wp) & M5;
            const u64 m1 = ((P1 >> j) ^ wp) & M5;
            zm[j]     = fma(bc, (double)(unsigned)__popcll(m0), zm[j]);
            zm[8 + j] = fma(bc, (double)(unsigned)__popcll(m1), zm[8 + j]);
        }
    }
    // t2 bit = (z >= 0) = (zm <= C2h)   [z = 2*(C2h - zm)]
    const double th = C2h[o];
    unsigned int tb = 0;
#pragma unroll
    for (int i = 0; i < 16; ++i) tb |= (zm[i] <= th ? 1u : 0u) << i;
    atomicAdd(&lcnt[o], (unsigned int)__popc(tb));

    const bool gp = (g2[o] >= 0.f);
    const size_t fbase = (size_t)b*1536 + (size_t)o*16 + (size_t)grp*4;
#pragma unroll
    for (int pj = 0; pj < 4; ++pj) {
        unsigned int four = ((tb >> (2*pj)) & 3u) | (((tb >> (8 + 2*pj)) & 3u) << 2);
        bool s = gp ? (four != 0u) : (four != 15u);
        s2[fbase + pj] = s ? (signed char)1 : (signed char)-1;
    }
    __syncthreads();
    if (t < 96) atomicAdd(&cnt2[t], lcnt[t]);
}

// ---------------------------------------------------------------- k4a: bn2 consts
__global__ __launch_bounds__(128) void k4a_consts2(
    const unsigned int* __restrict__ cnt2, const float* __restrict__ g2,
    const float* __restrict__ b2bn, double* __restrict__ alpha2,
    double* __restrict__ beta2)
{
    const int o = threadIdx.x;
    if (o < 96) {
        const double N2 = 4096.0 * 64.0;
        double m = (2.0 * (double)cnt2[o] - N2) / N2;
        double r = 1.0 / sqrt((1.0 - m*m) + EPSD);
        double g = (double)g2[o];
        alpha2[o] = (double)b2bn[o] - m * r * g;
        beta2[o]  = fabs(g) * r;
    }
}

// ---------------------------------------------------------------- k4ba: s2 column sums
__global__ __launch_bounds__(384) void k4ba_colsum3(
    const signed char* __restrict__ s2, int* __restrict__ cs3)
{
    const int t = threadIdx.x;
    const int seg = t % 96, rowg = t / 96;
    const int b0 = blockIdx.x * 32;
    unsigned int am0 = 0, am1 = 0, am2 = 0, am3 = 0;
#pragma unroll
    for (int k = 0; k < 8; ++k) {
        const int b = b0 + rowg*8 + k;
        const uint4 v = *(const uint4*)(s2 + (size_t)b*1536 + seg*16);
        am0 += (v.x >> 1) & 0x01010101u;
        am1 += (v.y >> 1) & 0x01010101u;
        am2 += (v.z >> 1) & 0x01010101u;
        am3 += (v.w >> 1) & 0x01010101u;
    }
    __shared__ unsigned int sm[384][4];
    sm[t][0] = am0; sm[t][1] = am1; sm[t][2] = am2; sm[t][3] = am3;
    __syncthreads();
    if (t < 96) {
#pragma unroll
        for (int d = 0; d < 4; ++d) {
            unsigned int m = sm[t][d] + sm[t+96][d] + sm[t+192][d] + sm[t+288][d];
#pragma unroll
            for (int bb = 0; bb < 4; ++bb) {
                int minus = (int)((m >> (8*bb)) & 0xFFu);
                atomicAdd(&cs3[t*16 + d*4 + bb], 32 - 2*minus);
            }
        }
    }
}

// ---------------------------------------------------------------- k4bb: A3,B3
__global__ __launch_bounds__(256) void k4bb_bn3(
    const int* __restrict__ cs3, const double* __restrict__ beta2,
    const float* __restrict__ g3, const float* __restrict__ b3bn,
    double* __restrict__ A3, double* __restrict__ B3)
{
    const int f = blockIdx.x * 256 + threadIdx.x;   // < 1536
    const double ms = (double)cs3[f] / 4096.0;
    const int c = f >> 4;
    const double b2v = beta2[c];
    const double var = b2v*b2v*(1.0 - ms*ms);
    const double r = 1.0 / sqrt(var + EPSD);
    const double g = (double)g3[f];
    A3[f] = (double)b3bn[f] - b2v * ms * r * g;
    B3[f] = b2v * r * g;
}

// ---------------------------------------------------------------- k5w: fc1 sign bytes
__global__ __launch_bounds__(256) void k5w_signs(
    const float* __restrict__ fw1, signed char* __restrict__ w1s)
{
    const int idx = blockIdx.x * 256 + threadIdx.x;   // < 393216 float4s
    const float4 v = ((const float4*)fw1)[idx];
    uchar4 o;
    o.x = (v.x >= 0.f) ? 0x01 : 0xFF;
    o.y = (v.y >= 0.f) ? 0x01 : 0xFF;
    o.z = (v.z >= 0.f) ? 0x01 : 0xFF;
    o.w = (v.w >= 0.f) ? 0x01 : 0xFF;
    ((uchar4*)w1s)[idx] = o;
}

// ---------------------------------------------------------------- k5: fc1 offsets (wave/j)
__global__ __launch_bounds__(256) void k5_c1j(
    const signed char* __restrict__ w1s, const float* __restrict__ fc1b,
    const double* __restrict__ A3, double* __restrict__ c1j)
{
    const int t = threadIdx.x;
    const int lane = t & 63, w = t >> 6;
    const int j = blockIdx.x * 4 + w;                 // grid 256
    double acc = 0.0;
#pragma unroll
    for (int q = 0; q < 6; ++q) {
        const int f0 = q*256 + lane*4;
        const unsigned int wb = *(const unsigned int*)(w1s + (size_t)j*1536 + f0);
#pragma unroll
        for (int bb = 0; bb < 4; ++bb) {
            const double a = A3[f0 + bb];
            acc += ((wb >> (8*bb)) & 0x80u) ? -a : a;
        }
    }
#pragma unroll
    for (int off = 32; off; off >>= 1) acc += __shfl_down(acc, off);
    if (lane == 0) c1j[j] = acc + (double)fc1b[j];
}

// ---------------------------------------------------------------- k6: fc1 GEMM
__global__ __launch_bounds__(256) void k6_fc1(
    const signed char* __restrict__ s2, const signed char* __restrict__ w1s,
    const double* __restrict__ B3, const double* __restrict__ c1j,
    signed char* __restrict__ t4)
{
    __shared__ signed char sS[64][80];
    __shared__ signed char sW[64][80];
    __shared__ double sB[64];
    const int bx = blockIdx.x & 63;        // b tile
    const int by = blockIdx.x >> 6;        // j tile
    const int b0 = bx * 64, j0 = by * 64;
    const int t = threadIdx.x;
    const int tb = t & 15, tj = t >> 4;
    double acc[4][4];
#pragma unroll
    for (int a = 0; a < 4; ++a)
#pragma unroll
        for (int bq = 0; bq < 4; ++bq) acc[a][bq] = 0.0;

    const int row = t >> 2, seg = t & 3;
    for (int fc = 0; fc < 1536; fc += 64) {
        __syncthreads();
        *(int4*)(&sS[row][seg*16]) = *(const int4*)(s2 + (size_t)(b0+row)*1536 + fc + seg*16);
        *(int4*)(&sW[row][seg*16]) = *(const int4*)(w1s + (size_t)(j0+row)*1536 + fc + seg*16);
        if (t < 64) sB[t] = B3[fc + t];
        __syncthreads();

        for (int f4 = 0; f4 < 64; f4 += 4) {
            unsigned int sa[4], wa[4];
#pragma unroll
            for (int ib = 0; ib < 4; ++ib)
                sa[ib] = *(const unsigned int*)(&sS[tb + 16*ib][f4]);
#pragma unroll
            for (int ij = 0; ij < 4; ++ij)
                wa[ij] = *(const unsigned int*)(&sW[tj + 16*ij][f4]);
#pragma unroll
            for (int u = 0; u < 4; ++u) {
                const double bv = sB[f4 + u];
                const int bvlo = __double2loint(bv);
                const int bvhi = __double2hiint(bv);
                const int sh = 24 - 8*u;   // byte u's bit7 -> bit31
                int svhi[4], wm[4];
#pragma unroll
                for (int ib = 0; ib < 4; ++ib)
                    svhi[ib] = bvhi ^ (int)((sa[ib] << sh) & 0x80000000u);
#pragma unroll
                for (int ij = 0; ij < 4; ++ij)
                    wm[ij] = (int)((wa[ij] << sh) & 0x80000000u);
#pragma unroll
                for (int ij = 0; ij < 4; ++ij)
#pragma unroll
                    for (int ib = 0; ib < 4; ++ib)
                        acc[ib][ij] += __hiloint2double(svhi[ib] ^ wm[ij], bvlo);
            }
        }
    }
#pragma unroll
    for (int ib = 0; ib < 4; ++ib)
#pragma unroll
        for (int ij = 0; ij < 4; ++ij) {
            const int b = b0 + tb + 16*ib;
            const int j = j0 + tj + 16*ij;
            const double p = acc[ib][ij] + c1j[j];
            t4[(size_t)b*1024 + j] = (p >= 0.0) ? (signed char)1 : (signed char)-1;
        }
}

// ---------------------------------------------------------------- k7a: t4 column sums
__global__ __launch_bounds__(256) void k7a_colsum4(
    const signed char* __restrict__ t4, int* __restrict__ cs4)
{
    const int t = threadIdx.x;
    const int seg = t & 63, rowg = t >> 6;
    const int b0 = blockIdx.x * 32;
    unsigned int am0 = 0, am1 = 0, am2 = 0, am3 = 0;
#pragma unroll
    for (int k = 0; k < 8; ++k) {
        const int b = b0 + rowg*8 + k;
        const uint4 v = *(const uint4*)(t4 + (size_t)b*1024 + seg*16);
        am0 += (v.x >> 1) & 0x01010101u;
        am1 += (v.y >> 1) & 0x01010101u;
        am2 += (v.z >> 1) & 0x01010101u;
        am3 += (v.w >> 1) & 0x01010101u;
    }
    __shared__ unsigned int sm[256][4];
    sm[t][0] = am0; sm[t][1] = am1; sm[t][2] = am2; sm[t][3] = am3;
    __syncthreads();
    if (t < 64) {
#pragma unroll
        for (int d = 0; d < 4; ++d) {
            unsigned int m = sm[t][d] + sm[t+64][d] + sm[t+128][d] + sm[t+192][d];
#pragma unroll
            for (int bb = 0; bb < 4; ++bb) {
                int minus = (int)((m >> (8*bb)) & 0xFFu);
                atomicAdd(&cs4[t*16 + d*4 + bb], 32 - 2*minus);
            }
        }
    }
}

// ---------------------------------------------------------------- k7b: A4,B4,C3
__global__ __launch_bounds__(1024) void k7b_bn4(
    const int* __restrict__ cs4, const float* __restrict__ g4,
    const float* __restrict__ b4bn, const float* __restrict__ fc2w,
    const float* __restrict__ fc2b, double* __restrict__ A4,
    double* __restrict__ B4, double* __restrict__ C3)
{
    __shared__ double sA4[1024];
    const int j = threadIdx.x;
    const double m = (double)cs4[j] / 4096.0;
    const double r = 1.0 / sqrt((1.0 - m*m) + EPSD);
    const double g = (double)g4[j];
    const double a4 = (double)b4bn[j] - m * r * g;
    A4[j] = a4;
    B4[j] = r * g;
    sA4[j] = a4;
    __syncthreads();
    if (j < 10) {
        const float* wr = fc2w + (size_t)j * 1024;
        double acc = (double)fc2b[j];
        for (int jj = 0; jj < 1024; ++jj)
            acc += (wr[jj] >= 0.f) ? sA4[jj] : -sA4[jj];
        C3[j] = acc;
    }
}

// ---------------------------------------------------------------- k8: fc2 (wave/output)
__global__ __launch_bounds__(256) void k8_fc2(
    const signed char* __restrict__ t4, const float* __restrict__ fc2w,
    const double* __restrict__ B4, const double* __restrict__ C3,
    float* __restrict__ out)
{
    const int t = threadIdx.x;
    const int lane = t & 63;
    const int wv = blockIdx.x * 4 + (t >> 6);        // < 40960
    const int b = wv / 10, kk = wv - b*10;
    const float* wr = fc2w + (size_t)kk * 1024;
    const signed char* tr = t4 + (size_t)b * 1024;
    double acc = 0.0;
#pragma unroll
    for (int q = 0; q < 4; ++q) {
        const int f0 = q*256 + lane*4;
        const float4 w4 = *(const float4*)(wr + f0);
        const unsigned int t4b = *(const unsigned int*)(tr + f0);
        const float wf[4] = {w4.x, w4.y, w4.z, w4.w};
#pragma unroll
        for (int bb = 0; bb < 4; ++bb) {
            const bool ws = (wf[bb] >= 0.f);
            const bool ts = ((t4b >> (8*bb)) & 0x80u) == 0;
            const double bv = B4[f0 + bb];
            acc += (ws == ts) ? bv : -bv;
        }
    }
#pragma unroll
    for (int off = 32; off; off >>= 1) acc += __shfl_down(acc, off);
    if (lane == 0) out[b*10 + kk] = (float)(acc + C3[kk]);
}

// ---------------------------------------------------------------- launcher
extern "C" void kernel_launch(void* const* d_in, const int* in_sizes, int n_in,
                              void* d_out, int out_size, void* d_ws, size_t ws_size,
                              hipStream_t stream)
{
    const float* x    = (const float*)d_in[0];
    const float* w1   = (const float*)d_in[1];
    const float* b1c  = (const float*)d_in[2];
    const float* g1   = (const float*)d_in[3];
    const float* b1bn = (const float*)d_in[4];
    const float* w2   = (const float*)d_in[5];
    const float* b2c  = (const float*)d_in[6];
    const float* g2   = (const float*)d_in[7];
    const float* b2bn = (const float*)d_in[8];
    const float* g3   = (const float*)d_in[9];
    const float* b3bn = (const float*)d_in[10];
    const float* fw1  = (const float*)d_in[11];
    const float* fb1  = (const float*)d_in[12];
    const float* g4   = (const float*)d_in[13];
    const float* b4bn = (const float*)d_in[14];
    const float* fw2  = (const float*)d_in[15];
    const float* fb2  = (const float*)d_in[16];

    char* ws = (char*)d_ws;
    unsigned int* cnt1   = (unsigned int*)(ws + O_CNT1);
    unsigned int* cnt2   = (unsigned int*)(ws + O_CNT2);
    int* cs3             = (int*)(ws + O_CS3);
    int* cs4             = (int*)(ws + O_CS4);
    double* alpha1       = (double*)(ws + O_ALPHA1);
    double* beta1        = (double*)(ws + O_BETA1);
    double* C2h          = (double*)(ws + O_C2H);
    double* alpha2       = (double*)(ws + O_ALPHA2);
    double* beta2        = (double*)(ws + O_BETA2);
    double* A3           = (double*)(ws + O_A3);
    double* B3           = (double*)(ws + O_B3);
    double* c1j          = (double*)(ws + O_C1J);
    double* A4           = (double*)(ws + O_A4);
    double* B4           = (double*)(ws + O_B4);
    double* C3           = (double*)(ws + O_C3);
    double* sumBeta      = (double*)(ws + O_SB);
    unsigned int* W2bits = (unsigned int*)(ws + O_W2BITS);
    unsigned short* s1p  = (unsigned short*)(ws + O_S1P);
    signed char* w1s     = (signed char*)(ws + O_W1S);
    signed char* s2      = (signed char*)(ws + O_S2);
    signed char* t4      = (signed char*)(ws + O_T4);

    hipMemsetAsync(ws, 0, ZERO_BYTES, stream);
    k1_conv1<<<4096, 256, 0, stream>>>(x, w1, b1c, g1, s1p, cnt1);
    k2a_consts1<<<1, 64, 0, stream>>>(g1, b1bn, cnt1, alpha1, beta1, sumBeta);
    k2b_w2bits<<<24, 256, 0, stream>>>(w2, W2bits);
    k2c_c2<<<96, 64, 0, stream>>>(w2, b2c, alpha1, sumBeta, C2h);
    k3_conv2<<<4096, 384, 0, stream>>>(s1p, W2bits, beta1, C2h, g2, s2, cnt2);
    k4a_consts2<<<1, 128, 0, stream>>>(cnt2, g2, b2bn, alpha2, beta2);
    k4ba_colsum3<<<128, 384, 0, stream>>>(s2, cs3);
    k4bb_bn3<<<6, 256, 0, stream>>>(cs3, beta2, g3, b3bn, A3, B3);
    k5w_signs<<<1536, 256, 0, stream>>>(fw1, w1s);
    k5_c1j<<<256, 256, 0, stream>>>(w1s, fb1, A3, c1j);
    k6_fc1<<<1024, 256, 0, stream>>>(s2, w1s, B3, c1j, t4);
    k7a_colsum4<<<128, 256, 0, stream>>>(t4, cs4);
    k7b_bn4<<<1, 1024, 0, stream>>>(cs4, g4, b4bn, fw2, fb2, A4, B4, C3);
    k8_fc2<<<10240, 256, 0, stream>>>(t4, fw2, B4, C3, (float*)d_out);

    (void)in_sizes; (void)n_in; (void)out_size; (void)ws_size; (void)alpha2;
}

// Round 4
// 894.102 us; speedup vs baseline: 2.3594x; 1.6394x over previous
//
#include <hip/hip_runtime.h>
#include <hip/hip_bf16.h>
#include <math.h>

// Binarized ConvNet, exact-sign implementation (round 4).
//  k1 : conv1 f64 -> pooled sign bits s1p + cnt1
//  k2a: bn1 consts + B1INT (beta*2^22 u32) + sumBeta
//  k2b: W2 sign bits spread to 60-bit stride-12 u64, [c][o]
//  k2c: C2HINT thresholds (i64, 2^22 scale)
//  k3 : conv2 XOR-popcount + u64 mad accumulate -> s2bf (bf16 +-1) + cnt2
//  k4a: bn2 consts   k4ba: s2bf column sums (sign-bit count)   k4bb: A3,B3,B3INT
//  k5m: fc1 limb planes W1L[5][1024][1536] bf16 (signed base-256 digits of w*B3int)
//  k5 : fc1 offsets c1jint (wave/j, reads fw1)
//  k6 : fc1 exact bf16-MFMA limb GEMM -> t4
//  k7a: t4 column sums   k7b: A4,B4,C3
//  k8 : fc2 (wave/output, f64)

static const double EPSD = 1e-5;
typedef unsigned long long u64;
typedef __attribute__((ext_vector_type(8))) short short8;
typedef __attribute__((ext_vector_type(4))) float floatx4;

#define FIXSCALE 4194304.0   // 2^22

// ---------------- ws layout (bytes) ----------------
#define O_CNT1   0
#define O_CNT2   256
#define O_CS3    1024
#define O_CS4    7168
#define ZERO_BYTES 11264
#define O_ALPHA1 11264
#define O_BETA1  11776
#define O_ALPHA2 13056
#define O_BETA2  13824
#define O_A3     14592      // 1536 f64
#define O_B3     26880      // 1536 f64
#define O_A4     47360
#define O_B4     55552
#define O_C3     63744      // 10 f64
#define O_SB     64000      // 1 f64
#define O_B1INT  64512      // 64 u32
#define O_C2HINT 64768      // 96 i64
#define O_W2S    65536      // 6144 u64 = 49152
#define O_B3INT  114688     // 1536 i64 = 12288
#define O_C1JINT 126976     // 1024 i64 = 8192
#define O_S1P    139264     // 4096*64*12 u16 = 6291456 (dead after k3)
#define O_W1L    139264     // 5*1024*1536 bf16 = 15728640 (overlays s1p; written after k3)
#define O_S2BF   15867904   // 4096*1536 bf16 = 12582912
#define O_T4     28450816   // 4096*1024 i8 = 4194304  (ends 32645120)
#define PLANE    (1024*1536)

// ---------------------------------------------------------------- k1: conv1
__global__ __launch_bounds__(256, 2) void k1_conv1(
    const float* __restrict__ x, const float* __restrict__ w1,
    const float* __restrict__ b1c, const float* __restrict__ g1,
    unsigned short* __restrict__ s1p, unsigned int* __restrict__ cnt1)
{
    __shared__ double X[28*28];
    __shared__ unsigned int redu[256];
    const int b = blockIdx.x;
    const int t = threadIdx.x;
    const float* xb = x + (size_t)b * 784;
    for (int i = t; i < 784; i += 256) X[i] = (double)xb[i];
    const int c = t & 63;
    const int grp = t >> 6;
    double w[25];
#pragma unroll
    for (int k = 0; k < 25; ++k) w[k] = (w1[c*25 + k] >= 0.f) ? 1.0 : -1.0;
    const double bias = (double)b1c[c];
    const bool gpos = (g1[c] >= 0.f);
    __syncthreads();

    unsigned int mycnt = 0;
    for (int pr = grp*3; pr < grp*3 + 3; ++pr) {
        double win[6][6];
#pragma unroll
        for (int r = 0; r < 6; ++r) {
            const double2* p = (const double2*)&X[(2*pr + r)*28];
            double2 a = p[0], bb = p[1], cc = p[2];
            win[r][0]=a.x; win[r][1]=a.y; win[r][2]=bb.x;
            win[r][3]=bb.y; win[r][4]=cc.x; win[r][5]=cc.y;
        }
        unsigned int rowbits = 0;
#pragma unroll
        for (int pc = 0; pc < 12; ++pc) {
            int nplus = 0;
#pragma unroll
            for (int d = 0; d < 4; ++d) {
                const int d0 = d >> 1, d1 = d & 1;
                double acc = 0.0;
#pragma unroll
                for (int ki = 0; ki < 5; ++ki)
#pragma unroll
                    for (int kj = 0; kj < 5; ++kj)
                        acc = fma(w[ki*5 + kj], win[d0 + ki][(2*pc + d1 + kj) % 6], acc);
                acc += bias;
                if (acc >= 0.0) ++nplus;
            }
            mycnt += (unsigned int)nplus;
            const bool s = gpos ? (nplus > 0) : (nplus < 4);
            rowbits |= (s ? 1u : 0u) << pc;
            if (pc < 11) {
#pragma unroll
                for (int r = 0; r < 6; ++r) {
                    const double2 nv = *(const double2*)&X[(2*pr + r)*28 + 2*pc + 6];
                    win[r][(2*pc + 6) % 6] = nv.x;
                    win[r][(2*pc + 7) % 6] = nv.y;
                }
            }
        }
        s1p[((size_t)b*64 + c)*12 + pr] = (unsigned short)rowbits;
    }
    redu[t] = mycnt;
    __syncthreads();
    if (t < 64) {
        unsigned int v = redu[t] + redu[t+64] + redu[t+128] + redu[t+192];
        atomicAdd(&cnt1[t], v);
    }
}

// ---------------------------------------------------------------- k2a: bn1 consts
__global__ __launch_bounds__(64) void k2a_consts1(
    const float* __restrict__ g1, const float* __restrict__ b1bn,
    const unsigned int* __restrict__ cnt1,
    double* __restrict__ alpha1, double* __restrict__ beta1,
    unsigned int* __restrict__ B1INT, double* __restrict__ sumBeta)
{
    const int t = threadIdx.x;
    const double N1 = 4096.0 * 576.0;
    double m = (2.0 * (double)cnt1[t] - N1) / N1;
    double r = 1.0 / sqrt((1.0 - m*m) + EPSD);
    double g = (double)g1[t];
    alpha1[t] = (double)b1bn[t] - m * r * g;
    const double bt = fabs(g) * r;
    beta1[t] = bt;
    B1INT[t] = (unsigned int)__double2ll_rn(bt * FIXSCALE);
    double s = bt;
#pragma unroll
    for (int off = 32; off; off >>= 1) s += __shfl_down(s, off);
    if (t == 0) sumBeta[0] = s;
}

// ---------------------------------------------------------------- k2b: W2 spread bits
__global__ __launch_bounds__(256) void k2b_w2bits(
    const float* __restrict__ w2, u64* __restrict__ W2S)
{
    const int e = blockIdx.x * 256 + threadIdx.x;   // < 6144, e = o*64+c
    const int o = e >> 6, c = e & 63;
    const float* wp = w2 + (size_t)e * 25;
    unsigned int bits = 0;
#pragma unroll
    for (int k = 0; k < 25; ++k) bits |= (wp[k] >= 0.f ? 1u : 0u) << k;
    const u64 sp = (u64)(bits & 31u)
                 | ((u64)((bits >> 5) & 31u) << 12)
                 | ((u64)((bits >> 10) & 31u) << 24)
                 | ((u64)((bits >> 15) & 31u) << 36)
                 | ((u64)((bits >> 20) & 31u) << 48);
    W2S[c*96 + o] = sp;
}

// ---------------------------------------------------------------- k2c: C2H thresholds
__global__ __launch_bounds__(64) void k2c_c2(
    const float* __restrict__ w2, const float* __restrict__ b2c,
    const double* __restrict__ alpha1, const double* __restrict__ sumBeta,
    long long* __restrict__ C2HINT)
{
    const int o = blockIdx.x;
    const int c = threadIdx.x;
    const float* wp = w2 + ((size_t)o*64 + c) * 25;
    double sw = 0.0;
#pragma unroll
    for (int k = 0; k < 25; ++k) sw += (wp[k] >= 0.f) ? 1.0 : -1.0;
    double part = sw * alpha1[c];
#pragma unroll
    for (int off = 32; off; off >>= 1) part += __shfl_down(part, off);
    if (c == 0) {
        const double c2h = (part + (double)b2c[o] + 25.0 * sumBeta[0]) * 0.5;
        C2HINT[o] = __double2ll_rn(c2h * FIXSCALE);
    }
}

// ---------------------------------------------------------------- k3: conv2
__global__ __launch_bounds__(384) void k3_conv2(
    const unsigned short* __restrict__ s1p, const u64* __restrict__ W2S,
    const unsigned int* __restrict__ B1INT, const long long* __restrict__ C2HINT,
    const float* __restrict__ g2, unsigned short* __restrict__ s2bf,
    unsigned int* __restrict__ cnt2)
{
    __shared__ unsigned int S32[384];
    __shared__ u64 WB[6144];
    __shared__ unsigned int sBint[64];
    __shared__ unsigned int lcnt[96];
    const int b = blockIdx.x;
    const int t = threadIdx.x;
    const unsigned int* sp32 = (const unsigned int*)(s1p + (size_t)b * 768);
    S32[t] = sp32[t];
    for (int i = t; i < 6144; i += 384) WB[i] = W2S[i];
    if (t < 64) sBint[t] = B1INT[t];
    if (t < 96) lcnt[t] = 0;
    __syncthreads();

    const int o = t % 96;
    const int grp = t / 96;
    const u64 M5 = 0x1FULL | (0x1FULL<<12) | (0x1FULL<<24) | (0x1FULL<<36) | (0x1FULL<<48);
    u64 zm[16];
#pragma unroll
    for (int i = 0; i < 16; ++i) zm[i] = 0ULL;

    for (int c = 0; c < 64; ++c) {
        const u64 wp = WB[c*96 + o];
        const unsigned int d0 = S32[c*6 + grp];
        const unsigned int d1 = S32[c*6 + grp + 1];
        const unsigned int d2 = S32[c*6 + grp + 2];
        const u64 r0 = d0 & 0xFFFFu, r1 = d0 >> 16;
        const u64 r2 = d1 & 0xFFFFu, r3 = d1 >> 16;
        const u64 r4 = d2 & 0xFFFFu, r5 = d2 >> 16;
        const u64 P0 = r0 | (r1 << 12) | (r2 << 24) | (r3 << 36) | (r4 << 48);
        const u64 P1 = (P0 >> 12) | (r5 << 48);
        const u64 Bc = (u64)sBint[c];
#pragma unroll
        for (int j = 0; j < 8; ++j) {
            const u64 m0 = ((P0 >> j) ^ wp) & M5;
            const u64 m1 = ((P1 >> j) ^ wp) & M5;
            zm[j]     += Bc * (u64)(unsigned)__popcll(m0);
            zm[8 + j] += Bc * (u64)(unsigned)__popcll(m1);
        }
    }
    const long long th = C2HINT[o];
    unsigned int tb = 0;
#pragma unroll
    for (int i = 0; i < 16; ++i) tb |= (((long long)zm[i] <= th) ? 1u : 0u) << i;
    atomicAdd(&lcnt[o], (unsigned int)__popc(tb));

    const bool gp = (g2[o] >= 0.f);
    const size_t fbase = (size_t)b*1536 + (size_t)o*16 + (size_t)grp*4;
#pragma unroll
    for (int pj = 0; pj < 4; ++pj) {
        unsigned int four = ((tb >> (2*pj)) & 3u) | (((tb >> (8 + 2*pj)) & 3u) << 2);
        bool s = gp ? (four != 0u) : (four != 15u);
        s2bf[fbase + pj] = s ? (unsigned short)0x3F80 : (unsigned short)0xBF80;
    }
    __syncthreads();
    if (t < 96) atomicAdd(&cnt2[t], lcnt[t]);
}

// ---------------------------------------------------------------- k4a: bn2 consts
__global__ __launch_bounds__(128) void k4a_consts2(
    const unsigned int* __restrict__ cnt2, const float* __restrict__ g2,
    const float* __restrict__ b2bn, double* __restrict__ alpha2,
    double* __restrict__ beta2)
{
    const int o = threadIdx.x;
    if (o < 96) {
        const double N2 = 4096.0 * 64.0;
        double m = (2.0 * (double)cnt2[o] - N2) / N2;
        double r = 1.0 / sqrt((1.0 - m*m) + EPSD);
        double g = (double)g2[o];
        alpha2[o] = (double)b2bn[o] - m * r * g;
        beta2[o]  = fabs(g) * r;
    }
}

// ---------------------------------------------------------------- k4ba: s2bf column sums
__global__ __launch_bounds__(192) void k4ba_colsum3(
    const unsigned short* __restrict__ s2bf, int* __restrict__ cs3)
{
    const int t = threadIdx.x;        // 192 segs x 8 cols
    const int b0 = blockIdx.x * 128;  // 32 blocks x 128 rows
    unsigned int a0 = 0, a1 = 0, a2 = 0, a3 = 0;   // 2x16-bit minus counts each
    for (int k = 0; k < 128; ++k) {
        const uint4 v = *(const uint4*)(s2bf + (size_t)(b0 + k)*1536 + t*8);
        a0 += (v.x >> 15) & 0x00010001u;
        a1 += (v.y >> 15) & 0x00010001u;
        a2 += (v.z >> 15) & 0x00010001u;
        a3 += (v.w >> 15) & 0x00010001u;
    }
    const int base = t * 8;
    atomicAdd(&cs3[base + 0], 128 - 2*(int)(a0 & 0xFFFFu));
    atomicAdd(&cs3[base + 1], 128 - 2*(int)(a0 >> 16));
    atomicAdd(&cs3[base + 2], 128 - 2*(int)(a1 & 0xFFFFu));
    atomicAdd(&cs3[base + 3], 128 - 2*(int)(a1 >> 16));
    atomicAdd(&cs3[base + 4], 128 - 2*(int)(a2 & 0xFFFFu));
    atomicAdd(&cs3[base + 5], 128 - 2*(int)(a2 >> 16));
    atomicAdd(&cs3[base + 6], 128 - 2*(int)(a3 & 0xFFFFu));
    atomicAdd(&cs3[base + 7], 128 - 2*(int)(a3 >> 16));
}

// ---------------------------------------------------------------- k4bb: A3,B3,B3INT
__global__ __launch_bounds__(256) void k4bb_bn3(
    const int* __restrict__ cs3, const double* __restrict__ beta2,
    const float* __restrict__ g3, const float* __restrict__ b3bn,
    double* __restrict__ A3, double* __restrict__ B3, long long* __restrict__ B3INT)
{
    const int f = blockIdx.x * 256 + threadIdx.x;   // < 1536
    const double ms = (double)cs3[f] / 4096.0;
    const int c = f >> 4;
    const double b2v = beta2[c];
    const double var = b2v*b2v*(1.0 - ms*ms);
    const double r = 1.0 / sqrt(var + EPSD);
    const double g = (double)g3[f];
    A3[f] = (double)b3bn[f] - b2v * ms * r * g;
    const double b3v = b2v * r * g;
    B3[f] = b3v;
    B3INT[f] = __double2ll_rn(b3v * FIXSCALE);
}

// ---------------------------------------------------------------- k5m: limb planes
__global__ __launch_bounds__(256) void k5m_limbs(
    const float* __restrict__ fw1, const long long* __restrict__ B3INT,
    unsigned short* __restrict__ W1L)
{
    const int idx = blockIdx.x * 256 + threadIdx.x;   // < 196608
    const int j = idx / 192, f0 = (idx % 192) * 8;
    const float4 wa = *(const float4*)(fw1 + (size_t)j*1536 + f0);
    const float4 wb = *(const float4*)(fw1 + (size_t)j*1536 + f0 + 4);
    const float wf[8] = {wa.x, wa.y, wa.z, wa.w, wb.x, wb.y, wb.z, wb.w};
    unsigned short ob[5][8];
#pragma unroll
    for (int i = 0; i < 8; ++i) {
        long long xx = B3INT[f0 + i];
        if (wf[i] < 0.f) xx = -xx;
#pragma unroll
        for (int l = 0; l < 5; ++l) {
            const int d = (int)(signed char)(xx & 0xFF);
            xx = (xx - d) >> 8;
            const float fd = (float)d;
            __hip_bfloat16 h = __float2bfloat16(fd);
            ob[l][i] = *(const unsigned short*)&h;
        }
    }
#pragma unroll
    for (int l = 0; l < 5; ++l) {
        uint4 v;
        v.x = (unsigned)ob[l][0] | ((unsigned)ob[l][1] << 16);
        v.y = (unsigned)ob[l][2] | ((unsigned)ob[l][3] << 16);
        v.z = (unsigned)ob[l][4] | ((unsigned)ob[l][5] << 16);
        v.w = (unsigned)ob[l][6] | ((unsigned)ob[l][7] << 16);
        *(uint4*)(W1L + (size_t)l*PLANE + (size_t)j*1536 + f0) = v;
    }
}

// ---------------------------------------------------------------- k5: fc1 offsets
__global__ __launch_bounds__(256) void k5_c1j(
    const float* __restrict__ fw1, const float* __restrict__ fc1b,
    const double* __restrict__ A3, long long* __restrict__ c1jint)
{
    const int t = threadIdx.x;
    const int lane = t & 63, w = t >> 6;
    const int j = blockIdx.x * 4 + w;                 // grid 256
    double acc = 0.0;
#pragma unroll
    for (int q = 0; q < 6; ++q) {
        const int f0 = q*256 + lane*4;
        const float4 w4 = *(const float4*)(fw1 + (size_t)j*1536 + f0);
        acc += (w4.x >= 0.f) ? A3[f0]   : -A3[f0];
        acc += (w4.y >= 0.f) ? A3[f0+1] : -A3[f0+1];
        acc += (w4.z >= 0.f) ? A3[f0+2] : -A3[f0+2];
        acc += (w4.w >= 0.f) ? A3[f0+3] : -A3[f0+3];
    }
#pragma unroll
    for (int off = 32; off; off >>= 1) acc += __shfl_down(acc, off);
    if (lane == 0) c1jint[j] = __double2ll_rn((acc + (double)fc1b[j]) * FIXSCALE);
}

// ---------------------------------------------------------------- k6: fc1 MFMA limb GEMM
__global__ __launch_bounds__(512, 2) void k6_fc1(
    const unsigned short* __restrict__ s2bf, const unsigned short* __restrict__ W1L,
    const long long* __restrict__ c1jint, signed char* __restrict__ t4)
{
    __shared__ short sA[128*72];       // 128 rows x 64 k, stride 72 (144B, 2-way banks)
    __shared__ short sB[5][64*72];
    const int t = threadIdx.x;
    const int b0 = (blockIdx.x & 31) * 128;
    const int j0 = (blockIdx.x >> 5) * 64;
    const int w = t >> 6, lane = t & 63;
    const int wr = w >> 1, wc = w & 1;
    const int l15 = lane & 15, l4 = lane >> 4;

    floatx4 acc[5][2][2];
#pragma unroll
    for (int l5 = 0; l5 < 5; ++l5)
#pragma unroll
        for (int m = 0; m < 2; ++m)
#pragma unroll
            for (int n = 0; n < 2; ++n) acc[l5][m][n] = (floatx4)0.f;

    const int br = t >> 3, bseg = t & 7;
    for (int step = 0; step < 24; ++step) {
        const int k0 = step * 64;
        __syncthreads();
#pragma unroll
        for (int ci = 0; ci < 2; ++ci) {
            const int chunk = t*2 + ci;
            const int ar = chunk >> 3, aseg = chunk & 7;
            const float4 v = *(const float4*)(s2bf + (size_t)(b0+ar)*1536 + k0 + aseg*8);
            *(float4*)(&sA[ar*72 + aseg*8]) = v;
        }
#pragma unroll
        for (int l5 = 0; l5 < 5; ++l5) {
            const float4 v = *(const float4*)(W1L + (size_t)l5*PLANE + (size_t)(j0+br)*1536 + k0 + bseg*8);
            *(float4*)(&sB[l5][br*72 + bseg*8]) = v;
        }
        __syncthreads();
#pragma unroll
        for (int ks = 0; ks < 2; ++ks) {
            short8 a[2];
#pragma unroll
            for (int m = 0; m < 2; ++m)
                a[m] = *(const short8*)(&sA[(wr*32 + m*16 + l15)*72 + ks*32 + l4*8]);
#pragma unroll
            for (int l5 = 0; l5 < 5; ++l5) {
#pragma unroll
                for (int n = 0; n < 2; ++n) {
                    const short8 bfr = *(const short8*)(&sB[l5][(wc*32 + n*16 + l15)*72 + ks*32 + l4*8]);
#pragma unroll
                    for (int m = 0; m < 2; ++m)
                        acc[l5][m][n] = __builtin_amdgcn_mfma_f32_16x16x32_bf16(a[m], bfr, acc[l5][m][n], 0, 0, 0);
                }
            }
        }
    }
    // epilogue: exact integer recombination
#pragma unroll
    for (int n = 0; n < 2; ++n) {
        const int j = j0 + wc*32 + n*16 + l15;
        const long long cj = c1jint[j];
#pragma unroll
        for (int m = 0; m < 2; ++m) {
#pragma unroll
            for (int q = 0; q < 4; ++q) {
                long long z = cj;
#pragma unroll
                for (int l5 = 0; l5 < 5; ++l5)
                    z += ((long long)acc[l5][m][n][q]) << (8*l5);
                const int b = b0 + wr*32 + m*16 + l4*4 + q;
                t4[(size_t)b*1024 + j] = (z >= 0) ? (signed char)1 : (signed char)-1;
            }
        }
    }
}

// ---------------------------------------------------------------- k7a: t4 column sums
__global__ __launch_bounds__(256) void k7a_colsum4(
    const signed char* __restrict__ t4, int* __restrict__ cs4)
{
    const int t = threadIdx.x;
    const int seg = t & 63, rowg = t >> 6;
    const int b0 = blockIdx.x * 32;
    unsigned int am0 = 0, am1 = 0, am2 = 0, am3 = 0;
#pragma unroll
    for (int k = 0; k < 8; ++k) {
        const int b = b0 + rowg*8 + k;
        const uint4 v = *(const uint4*)(t4 + (size_t)b*1024 + seg*16);
        am0 += (v.x >> 1) & 0x01010101u;
        am1 += (v.y >> 1) & 0x01010101u;
        am2 += (v.z >> 1) & 0x01010101u;
        am3 += (v.w >> 1) & 0x01010101u;
    }
    __shared__ unsigned int sm[256][4];
    sm[t][0] = am0; sm[t][1] = am1; sm[t][2] = am2; sm[t][3] = am3;
    __syncthreads();
    if (t < 64) {
#pragma unroll
        for (int d = 0; d < 4; ++d) {
            unsigned int m = sm[t][d] + sm[t+64][d] + sm[t+128][d] + sm[t+192][d];
#pragma unroll
            for (int bb = 0; bb < 4; ++bb) {
                int minus = (int)((m >> (8*bb)) & 0xFFu);
                atomicAdd(&cs4[t*16 + d*4 + bb], 32 - 2*minus);
            }
        }
    }
}

// ---------------------------------------------------------------- k7b: A4,B4,C3
__global__ __launch_bounds__(1024) void k7b_bn4(
    const int* __restrict__ cs4, const float* __restrict__ g4,
    const float* __restrict__ b4bn, const float* __restrict__ fc2w,
    const float* __restrict__ fc2b, double* __restrict__ A4,
    double* __restrict__ B4, double* __restrict__ C3)
{
    __shared__ double sA4[1024];
    const int j = threadIdx.x;
    const double m = (double)cs4[j] / 4096.0;
    const double r = 1.0 / sqrt((1.0 - m*m) + EPSD);
    const double g = (double)g4[j];
    const double a4 = (double)b4bn[j] - m * r * g;
    A4[j] = a4;
    B4[j] = r * g;
    sA4[j] = a4;
    __syncthreads();
    if (j < 10) {
        const float* wr = fc2w + (size_t)j * 1024;
        double acc = (double)fc2b[j];
        for (int jj = 0; jj < 1024; ++jj)
            acc += (wr[jj] >= 0.f) ? sA4[jj] : -sA4[jj];
        C3[j] = acc;
    }
}

// ---------------------------------------------------------------- k8: fc2
__global__ __launch_bounds__(256) void k8_fc2(
    const signed char* __restrict__ t4, const float* __restrict__ fc2w,
    const double* __restrict__ B4, const double* __restrict__ C3,
    float* __restrict__ out)
{
    const int t = threadIdx.x;
    const int lane = t & 63;
    const int wv = blockIdx.x * 4 + (t >> 6);        // < 40960
    const int b = wv / 10, kk = wv - b*10;
    const float* wr = fc2w + (size_t)kk * 1024;
    const signed char* tr = t4 + (size_t)b * 1024;
    double acc = 0.0;
#pragma unroll
    for (int q = 0; q < 4; ++q) {
        const int f0 = q*256 + lane*4;
        const float4 w4 = *(const float4*)(wr + f0);
        const unsigned int t4b = *(const unsigned int*)(tr + f0);
        const float wf[4] = {w4.x, w4.y, w4.z, w4.w};
#pragma unroll
        for (int bb = 0; bb < 4; ++bb) {
            const bool ws = (wf[bb] >= 0.f);
            const bool ts = ((t4b >> (8*bb)) & 0x80u) == 0;
            const double bv = B4[f0 + bb];
            acc += (ws == ts) ? bv : -bv;
        }
    }
#pragma unroll
    for (int off = 32; off; off >>= 1) acc += __shfl_down(acc, off);
    if (lane == 0) out[b*10 + kk] = (float)(acc + C3[kk]);
}

// ---------------------------------------------------------------- launcher
extern "C" void kernel_launch(void* const* d_in, const int* in_sizes, int n_in,
                              void* d_out, int out_size, void* d_ws, size_t ws_size,
                              hipStream_t stream)
{
    const float* x    = (const float*)d_in[0];
    const float* w1   = (const float*)d_in[1];
    const float* b1c  = (const float*)d_in[2];
    const float* g1   = (const float*)d_in[3];
    const float* b1bn = (const float*)d_in[4];
    const float* w2   = (const float*)d_in[5];
    const float* b2c  = (const float*)d_in[6];
    const float* g2   = (const float*)d_in[7];
    const float* b2bn = (const float*)d_in[8];
    const float* g3   = (const float*)d_in[9];
    const float* b3bn = (const float*)d_in[10];
    const float* fw1  = (const float*)d_in[11];
    const float* fb1  = (const float*)d_in[12];
    const float* g4   = (const float*)d_in[13];
    const float* b4bn = (const float*)d_in[14];
    const float* fw2  = (const float*)d_in[15];
    const float* fb2  = (const float*)d_in[16];

    char* ws = (char*)d_ws;
    unsigned int* cnt1   = (unsigned int*)(ws + O_CNT1);
    unsigned int* cnt2   = (unsigned int*)(ws + O_CNT2);
    int* cs3             = (int*)(ws + O_CS3);
    int* cs4             = (int*)(ws + O_CS4);
    double* alpha1       = (double*)(ws + O_ALPHA1);
    double* beta1        = (double*)(ws + O_BETA1);
    double* alpha2       = (double*)(ws + O_ALPHA2);
    double* beta2        = (double*)(ws + O_BETA2);
    double* A3           = (double*)(ws + O_A3);
    double* B3           = (double*)(ws + O_B3);
    double* A4           = (double*)(ws + O_A4);
    double* B4           = (double*)(ws + O_B4);
    double* C3           = (double*)(ws + O_C3);
    double* sumBeta      = (double*)(ws + O_SB);
    unsigned int* B1INT  = (unsigned int*)(ws + O_B1INT);
    long long* C2HINT    = (long long*)(ws + O_C2HINT);
    u64* W2S             = (u64*)(ws + O_W2S);
    long long* B3INT     = (long long*)(ws + O_B3INT);
    long long* c1jint    = (long long*)(ws + O_C1JINT);
    unsigned short* s1p  = (unsigned short*)(ws + O_S1P);
    unsigned short* W1L  = (unsigned short*)(ws + O_W1L);
    unsigned short* s2bf = (unsigned short*)(ws + O_S2BF);
    signed char* t4      = (signed char*)(ws + O_T4);

    hipMemsetAsync(ws, 0, ZERO_BYTES, stream);
    k1_conv1<<<4096, 256, 0, stream>>>(x, w1, b1c, g1, s1p, cnt1);
    k2a_consts1<<<1, 64, 0, stream>>>(g1, b1bn, cnt1, alpha1, beta1, B1INT, sumBeta);
    k2b_w2bits<<<24, 256, 0, stream>>>(w2, W2S);
    k2c_c2<<<96, 64, 0, stream>>>(w2, b2c, alpha1, sumBeta, C2HINT);
    k3_conv2<<<4096, 384, 0, stream>>>(s1p, W2S, B1INT, C2HINT, g2, s2bf, cnt2);
    k4a_consts2<<<1, 128, 0, stream>>>(cnt2, g2, b2bn, alpha2, beta2);
    k4ba_colsum3<<<32, 192, 0, stream>>>(s2bf, cs3);
    k4bb_bn3<<<6, 256, 0, stream>>>(cs3, beta2, g3, b3bn, A3, B3, B3INT);
    k5m_limbs<<<768, 256, 0, stream>>>(fw1, B3INT, W1L);
    k5_c1j<<<256, 256, 0, stream>>>(fw1, fb1, A3, c1jint);
    k6_fc1<<<512, 512, 0, stream>>>(s2bf, W1L, c1jint, t4);
    k7a_colsum4<<<128, 256, 0, stream>>>(t4, cs4);
    k7b_bn4<<<1, 1024, 0, stream>>>(cs4, g4, b4bn, fw2, fb2, A4, B4, C3);
    k8_fc2<<<10240, 256, 0, stream>>>(t4, fw2, B4, C3, (float*)d_out);

    (void)in_sizes; (void)n_in; (void)out_size; (void)ws_size;
    (void)beta1; (void)alpha2; (void)B3;
}